// Round 18
// baseline (144.647 us; speedup 1.0000x reference)
//
#include <hip/hip_runtime.h>
#include <math.h>

#define D  48
#define DQ 12        // D/4
#define SPAN 128     // nodes per bucket
#define SHIFT 7      // log2(SPAN)
#define PCH  8192    // edges per hist/partition block
#define PTH  512     // threads for hist/part
#define NPB  16      // nodes per k_fuse block (16 threads/node)
#define WSTR 52      // LDS row stride (16B-aligned, low-conflict float4 reads)
#define YROW 16      // ybf row: 12 x ushort4 bf16(g*x) + slot12 (g-1 fp32) + pad to 128B

constexpr float F_EPS   = 1e-15f;
constexpr float MAXNORM = 1.0f - 1e-5f;

__device__ __forceinline__ float clampabs(float x) {
    return (x >= 0.0f) ? fmaxf(x, 1e-10f) : fminf(x, -1e-10f);
}

__device__ __forceinline__ unsigned short f2bf(float f) {
    unsigned u = __float_as_uint(f);
    u += 0x7FFFu + ((u >> 16) & 1u);
    return (unsigned short)(u >> 16);
}

__device__ __forceinline__ float bf2f(unsigned short u) {
    return __uint_as_float(((unsigned)u) << 16);
}

__device__ __forceinline__ float gm1f(ushort4 a) {   // fp32 packed in .x/.y
    return __uint_as_float((unsigned)a.x | ((unsigned)a.y << 16));
}

// fast tanh for x>=0 via hw exp (overflow-safe); fast atanh for 0<=x<1
__device__ __forceinline__ float fast_tanh(float x) {
    float e = __expf(2.0f * x);
    return 1.0f - __fdividef(2.0f, e + 1.0f);
}
__device__ __forceinline__ float fast_atanh(float x) {
    x = fminf(x, 1.0f - 1e-7f);
    return 0.5f * __logf(__fdividef(1.0f + x, 1.0f - x));
}

// ---------- per-node gamma + zero bucket histogram ----------
__global__ void k_gamma(const float* __restrict__ x, float* __restrict__ gam,
                        int* __restrict__ ghist, int n, int nb)
{
    int i = blockIdx.x * blockDim.x + threadIdx.x;
    if (i < nb) ghist[i] = 0;
    if (i >= n) return;
    const float4* xr = reinterpret_cast<const float4*>(x) + (size_t)i * DQ;
    float s = 0.0f;
#pragma unroll
    for (int q = 0; q < DQ; ++q) {
        float4 v = xr[q];
        s += v.x * v.x + v.y * v.y + v.z * v.z + v.w * v.w;
    }
    gam[i] = 2.0f / fmaxf(1.0f - s, F_EPS);
}

// ---------- bucket histogram (LDS-staged) ----------
__global__ __launch_bounds__(PTH) void k_hist(const int* __restrict__ dst,
                                              int* __restrict__ ghist, int E, int nb)
{
    __shared__ int h[1024];
    int t = threadIdx.x;
    for (int i = t; i < 1024; i += PTH) h[i] = 0;
    __syncthreads();
    int base = blockIdx.x * PCH;
#pragma unroll 4
    for (int k = 0; k < PCH / PTH; ++k) {
        int i = base + k * PTH + t;
        if (i < E) {
            unsigned b = ((unsigned)dst[i]) >> SHIFT;
            if (b < 1024u) atomicAdd(&h[b], 1);
        }
    }
    __syncthreads();
    for (int i = t; i < nb; i += PTH) {
        int c = h[i];
        if (c) atomicAdd(&ghist[i], c);
    }
}

// ---------- exclusive scan of bucket counts (single block, nb <= 1024) ----------
__global__ __launch_bounds__(1024) void k_scanb(const int* __restrict__ ghist,
                                                int* __restrict__ gstart,
                                                int* __restrict__ gcur, int nb, int E)
{
    __shared__ int sh[1024];
    int t = threadIdx.x;
    int v = (t < nb) ? ghist[t] : 0;
    sh[t] = v;
    __syncthreads();
    for (int off = 1; off < 1024; off <<= 1) {
        int a = sh[t];
        int b = (t >= off) ? sh[t - off] : 0;
        __syncthreads();
        sh[t] = a + b;
        __syncthreads();
    }
    if (t < nb) { int s = sh[t] - v; gstart[t] = s; gcur[t] = s; }
    if (t == 0) gstart[nb] = E;
}

// ---------- partition (pure streaming) ----------
__global__ __launch_bounds__(PTH) void k_part(const int* __restrict__ src,
                                              const int* __restrict__ dst,
                                              const float* __restrict__ w,
                                              int* __restrict__ gcur,
                                              int2* __restrict__ seg, int E, int nb)
{
    __shared__ int hist[1024];
    __shared__ int base_[1024];
    __shared__ int lcur[1024];
    int t = threadIdx.x;
    for (int i = t; i < 1024; i += PTH) { hist[i] = 0; base_[i] = 0; lcur[i] = 0; }
    __syncthreads();
    int b0 = blockIdx.x * PCH;
#pragma unroll 4
    for (int k = 0; k < PCH / PTH; ++k) {
        int i = b0 + k * PTH + t;
        if (i < E) {
            unsigned b = ((unsigned)dst[i]) >> SHIFT;
            if (b < 1024u) atomicAdd(&hist[b], 1);
        }
    }
    __syncthreads();
    for (int i = t; i < nb; i += PTH) {
        int c = hist[i];
        if (c) base_[i] = atomicAdd(&gcur[i], c);
    }
    __syncthreads();
#pragma unroll 4
    for (int k = 0; k < PCH / PTH; ++k) {
        int i = b0 + k * PTH + t;
        if (i < E) {
            int d = dst[i];
            unsigned b = ((unsigned)d) >> SHIFT;
            if (b < 1024u) {
                int pos = base_[b] + atomicAdd(&lcur[b], 1);
                if (pos >= 0 && pos < E) {
                    int2 r;
                    r.x = ((d & (SPAN - 1)) << 24) | (src[i] & 0xFFFFFF);
                    r.y = __float_as_int(w[i]);
                    seg[pos] = r;
                }
            }
        }
    }
}

// ---------- per-bucket LDS counting sort -> exact per-node order + starts ----------
__global__ __launch_bounds__(256) void k_sortb(
    const int2* __restrict__ seg, const int* __restrict__ gstart,
    int* __restrict__ starts, int2* __restrict__ seg2, int n, int E)
{
    __shared__ int hist[SPAN];
    __shared__ int sb[SPAN];
    __shared__ int cur[SPAN];
    int b = blockIdx.x;
    int t = threadIdx.x;
    if (b == 0 && t == 0) starts[n] = E;
    int segL = gstart[b], segR = gstart[b + 1];
    if (segL < 0) segL = 0;
    if (segR > E) segR = E;
    if (t < SPAN) hist[t] = 0;
    __syncthreads();
    {
        int j = segL + t;
        for (; j + 768 < segR; j += 1024) {
            unsigned d0 = ((unsigned)seg[j      ].x) >> 24;
            unsigned d1 = ((unsigned)seg[j + 256].x) >> 24;
            unsigned d2 = ((unsigned)seg[j + 512].x) >> 24;
            unsigned d3 = ((unsigned)seg[j + 768].x) >> 24;
            atomicAdd(&hist[d0], 1);
            atomicAdd(&hist[d1], 1);
            atomicAdd(&hist[d2], 1);
            atomicAdd(&hist[d3], 1);
        }
        for (; j < segR; j += 256) {
            unsigned dl = ((unsigned)seg[j].x) >> 24;
            atomicAdd(&hist[dl], 1);
        }
    }
    __syncthreads();
    if (t < SPAN) sb[t] = hist[t];
    __syncthreads();
    for (int off = 1; off < SPAN; off <<= 1) {
        int a = 0;
        if (t < SPAN) { a = sb[t]; if (t >= off) a += sb[t - off]; }
        __syncthreads();
        if (t < SPAN) sb[t] = a;
        __syncthreads();
    }
    if (t < SPAN) {
        int ls = sb[t] - hist[t];
        cur[t] = segL + ls;
        int node = b * SPAN + t;
        if (node < n) starts[node] = segL + ls;
    }
    __syncthreads();
    {
        int j = segL + t;
        for (; j + 768 < segR; j += 1024) {
            int2 r0 = seg[j      ];
            int2 r1 = seg[j + 256];
            int2 r2 = seg[j + 512];
            int2 r3 = seg[j + 768];
            int p0 = atomicAdd(&cur[((unsigned)r0.x) >> 24], 1);
            int p1 = atomicAdd(&cur[((unsigned)r1.x) >> 24], 1);
            int p2 = atomicAdd(&cur[((unsigned)r2.x) >> 24], 1);
            int p3 = atomicAdd(&cur[((unsigned)r3.x) >> 24], 1);
            if (p0 >= 0 && p0 < E) seg2[p0] = make_int2(r0.x & 0xFFFFFF, r0.y);
            if (p1 >= 0 && p1 < E) seg2[p1] = make_int2(r1.x & 0xFFFFFF, r1.y);
            if (p2 >= 0 && p2 < E) seg2[p2] = make_int2(r2.x & 0xFFFFFF, r2.y);
            if (p3 >= 0 && p3 < E) seg2[p3] = make_int2(r3.x & 0xFFFFFF, r3.y);
        }
        for (; j < segR; j += 256) {
            int2 r = seg[j];
            int pos = atomicAdd(&cur[((unsigned)r.x) >> 24], 1);
            if (pos >= 0 && pos < E) seg2[pos] = make_int2(r.x & 0xFFFFFF, r.y);
        }
    }
}

// ---------- k_prep: 128B-aligned ybf rows: 12x bf16(g*x) + fp32(g-1) + pad ----------
__global__ __launch_bounds__(256) void k_prep(const float* __restrict__ x,
                                              const float* __restrict__ gam,
                                              ushort4* __restrict__ ybf, int n)
{
    long long t = (long long)blockIdx.x * blockDim.x + threadIdx.x;
    int node = (int)(t / YROW);
    if (node >= n) return;
    int slot = (int)(t % YROW);
    float g = gam[node];
    ushort4 o;
    if (slot < 12) {
        float4 v = reinterpret_cast<const float4*>(x)[(size_t)node * DQ + slot];
        o.x = f2bf(v.x * g);
        o.y = f2bf(v.y * g);
        o.z = f2bf(v.z * g);
        o.w = f2bf(v.w * g);
    } else if (slot == 12) {
        unsigned u = __float_as_uint(g - 1.0f);
        o.x = (unsigned short)(u & 0xFFFFu);
        o.y = (unsigned short)(u >> 16);
        o.z = 0; o.w = 0;
    } else {
        o.x = 0; o.y = 0; o.z = 0; o.w = 0;   // pad
    }
    ybf[(size_t)node * YROW + slot] = o;
}

// ---------- fused gather + node math: 16 lanes per node, 8-wide gather ----------
__global__ __launch_bounds__(256) void k_fuse(
    const ushort4* __restrict__ ybf,
    const int* __restrict__ starts,
    const int2* __restrict__ srec,
    const float* __restrict__ h_init,
    const float* __restrict__ Wm,
    const float* __restrict__ bias,
    float* __restrict__ out, int n, int E)
{
    __shared__ float Ws[D * WSTR];
    __shared__ float bs[D];
    __shared__ float aLds[NPB][WSTR];
    int t = threadIdx.x;
    for (int k = t; k < D * D; k += 256) Ws[(k / D) * WSTR + (k % D)] = Wm[k];
    if (t < D) bs[t] = bias[t];

    int grp = t >> 4;
    int lane = t & 15;
    int i = blockIdx.x * NPB + grp;
    bool act = (i < n);

    auto gsum = [](float v) {
        v += __shfl_xor(v, 1, 16);
        v += __shfl_xor(v, 2, 16);
        v += __shfl_xor(v, 4, 16);
        v += __shfl_xor(v, 8, 16);
        return v;
    };
    auto hmp_scale = [](float s) {     // tanh(0.5*atanh(m))/m with project
        float nrm = sqrtf(s);
        float ncl = fmaxf(nrm, F_EPS);
        float m = fminf(ncl, 1.0f - 1e-7f);
        float sc = __fdividef(__fdividef(m, ncl),
                              1.0f + sqrtf(fmaxf(1.0f - m * m, 0.0f)));
        float rn = nrm * sc;
        if (rn > MAXNORM) sc *= MAXNORM / fmaxf(rn, F_EPS);
        return sc;
    };

    // ---- gather: lanes 0-11 num fragments; lanes 12-15 split den 4 ways
    int j0 = 0, j1 = 0;
    if (act) {
        j0 = starts[i]; j1 = starts[i + 1];
        if (j0 < 0) j0 = 0;
        if (j1 > E) j1 = E;
    }
    float4 acc = make_float4(0.f, 0.f, 0.f, 0.f);
    float dacc = 0.f;
    int j = j0;
    // 8-wide main loop: 8 independent row fetches in flight per num-lane;
    // den lanes (12-15) each fetch their 2 of the 8 gamma slots.
    for (; j + 7 < j1; j += 8) {
        if (lane < 12) {
            int2 r0 = srec[j];
            int2 r1 = srec[j + 1];
            int2 r2 = srec[j + 2];
            int2 r3 = srec[j + 3];
            int2 r4 = srec[j + 4];
            int2 r5 = srec[j + 5];
            int2 r6 = srec[j + 6];
            int2 r7 = srec[j + 7];
            ushort4 a0 = ybf[(size_t)r0.x * YROW + lane];
            ushort4 a1 = ybf[(size_t)r1.x * YROW + lane];
            ushort4 a2 = ybf[(size_t)r2.x * YROW + lane];
            ushort4 a3 = ybf[(size_t)r3.x * YROW + lane];
            ushort4 a4 = ybf[(size_t)r4.x * YROW + lane];
            ushort4 a5 = ybf[(size_t)r5.x * YROW + lane];
            ushort4 a6 = ybf[(size_t)r6.x * YROW + lane];
            ushort4 a7 = ybf[(size_t)r7.x * YROW + lane];
            float w0 = __int_as_float(r0.y);
            float w1 = __int_as_float(r1.y);
            float w2 = __int_as_float(r2.y);
            float w3 = __int_as_float(r3.y);
            float w4 = __int_as_float(r4.y);
            float w5 = __int_as_float(r5.y);
            float w6 = __int_as_float(r6.y);
            float w7 = __int_as_float(r7.y);
            acc.x = fmaf(w0, bf2f(a0.x), acc.x);
            acc.y = fmaf(w0, bf2f(a0.y), acc.y);
            acc.z = fmaf(w0, bf2f(a0.z), acc.z);
            acc.w = fmaf(w0, bf2f(a0.w), acc.w);
            acc.x = fmaf(w1, bf2f(a1.x), acc.x);
            acc.y = fmaf(w1, bf2f(a1.y), acc.y);
            acc.z = fmaf(w1, bf2f(a1.z), acc.z);
            acc.w = fmaf(w1, bf2f(a1.w), acc.w);
            acc.x = fmaf(w2, bf2f(a2.x), acc.x);
            acc.y = fmaf(w2, bf2f(a2.y), acc.y);
            acc.z = fmaf(w2, bf2f(a2.z), acc.z);
            acc.w = fmaf(w2, bf2f(a2.w), acc.w);
            acc.x = fmaf(w3, bf2f(a3.x), acc.x);
            acc.y = fmaf(w3, bf2f(a3.y), acc.y);
            acc.z = fmaf(w3, bf2f(a3.z), acc.z);
            acc.w = fmaf(w3, bf2f(a3.w), acc.w);
            acc.x = fmaf(w4, bf2f(a4.x), acc.x);
            acc.y = fmaf(w4, bf2f(a4.y), acc.y);
            acc.z = fmaf(w4, bf2f(a4.z), acc.z);
            acc.w = fmaf(w4, bf2f(a4.w), acc.w);
            acc.x = fmaf(w5, bf2f(a5.x), acc.x);
            acc.y = fmaf(w5, bf2f(a5.y), acc.y);
            acc.z = fmaf(w5, bf2f(a5.z), acc.z);
            acc.w = fmaf(w5, bf2f(a5.w), acc.w);
            acc.x = fmaf(w6, bf2f(a6.x), acc.x);
            acc.y = fmaf(w6, bf2f(a6.y), acc.y);
            acc.z = fmaf(w6, bf2f(a6.z), acc.z);
            acc.w = fmaf(w6, bf2f(a6.w), acc.w);
            acc.x = fmaf(w7, bf2f(a7.x), acc.x);
            acc.y = fmaf(w7, bf2f(a7.y), acc.y);
            acc.z = fmaf(w7, bf2f(a7.z), acc.z);
            acc.w = fmaf(w7, bf2f(a7.w), acc.w);
        } else {
            int ll = lane - 12;
            int2 ra = srec[j + ll];
            int2 rb = srec[j + 4 + ll];
            ushort4 ga = ybf[(size_t)ra.x * YROW + 12];
            ushort4 gb = ybf[(size_t)rb.x * YROW + 12];
            dacc += fabsf(__int_as_float(ra.y)) * gm1f(ga)
                  + fabsf(__int_as_float(rb.y)) * gm1f(gb);
        }
    }
    // tail: lanes 0-11 num, lane 12 den
    for (; j < j1; ++j) {
        int2 r0 = srec[j];
        float w0 = __int_as_float(r0.y);
        if (lane < 12) {
            ushort4 a0 = ybf[(size_t)r0.x * YROW + lane];
            acc.x = fmaf(w0, bf2f(a0.x), acc.x);
            acc.y = fmaf(w0, bf2f(a0.y), acc.y);
            acc.z = fmaf(w0, bf2f(a0.z), acc.z);
            acc.w = fmaf(w0, bf2f(a0.w), acc.w);
        } else if (lane == 12) {
            ushort4 a0 = ybf[(size_t)r0.x * YROW + 12];
            dacc += fabsf(w0) * gm1f(a0);
        }
    }

    float dv = gsum(dacc);     // lanes 0-11 contribute 0; all lanes get den

    // redistribute num fragments (4p..4p+3) -> per-lane elems {l,l+16,l+32}
    if (lane < 12)
        reinterpret_cast<float4*>(&aLds[grp][0])[lane] = acc;
    __syncthreads();

    // ---- node math
    float dinv = 1.0f / clampabs(dv);
    float a0 = aLds[grp][lane]      * dinv;
    float a1 = aLds[grp][lane + 16] * dinv;
    float a2 = aLds[grp][lane + 32] * dinv;

    float s1 = gsum(a0 * a0 + a1 * a1 + a2 * a2);
    float sc1 = hmp_scale(s1);
    a0 *= sc1; a1 *= sc1; a2 *= sc1;
    float sa = s1 * sc1 * sc1;

    float s2, sc2;
    {
        float b0 = 0.f, b1 = 0.f, b2 = 0.f;
        if (act) {
            const float* hr = h_init + (size_t)i * D;
            b0 = hr[lane];
            b1 = hr[lane + 16];
            b2 = hr[lane + 32];
        }
        float sb = gsum(b0 * b0 + b1 * b1 + b2 * b2);
        float ga = 2.0f / fmaxf(1.0f - sa, F_EPS);
        float gb = 2.0f / fmaxf(1.0f - sb, F_EPS);
        const float wa = 0.9f, wb = 0.1f;
        float dinv2 = 1.0f / clampabs(wa * (ga - 1.0f) + wb * (gb - 1.0f));
        float ca = wa * ga * dinv2, cb = wb * gb * dinv2;
        a0 = ca * a0 + cb * b0;
        a1 = ca * a1 + cb * b1;
        a2 = ca * a2 + cb * b2;
        s2 = gsum(a0 * a0 + a1 * a1 + a2 * a2);
        sc2 = hmp_scale(s2);
        a0 *= sc2; a1 *= sc2; a2 *= sc2;
    }
    float xn = fmaxf(sqrtf(s2) * sc2, F_EPS);

    // restage projected a for the float4 matvec
    aLds[grp][lane]      = a0;
    aLds[grp][lane + 16] = a1;
    aLds[grp][lane + 32] = a2;
    __syncthreads();

    const float4* av4 = reinterpret_cast<const float4*>(&aLds[grp][0]);
    const float4* w04 = reinterpret_cast<const float4*>(&Ws[lane * WSTR]);
    const float4* w14 = reinterpret_cast<const float4*>(&Ws[(lane + 16) * WSTR]);
    const float4* w24 = reinterpret_cast<const float4*>(&Ws[(lane + 32) * WSTR]);
    float acc0 = 0.f, acc1 = 0.f, acc2 = 0.f;
#pragma unroll
    for (int kq = 0; kq < DQ; ++kq) {
        float4 a4 = av4[kq];
        float4 x0 = w04[kq];
        float4 x1 = w14[kq];
        float4 x2 = w24[kq];
        acc0 = fmaf(x0.x, a4.x, acc0); acc0 = fmaf(x0.y, a4.y, acc0);
        acc0 = fmaf(x0.z, a4.z, acc0); acc0 = fmaf(x0.w, a4.w, acc0);
        acc1 = fmaf(x1.x, a4.x, acc1); acc1 = fmaf(x1.y, a4.y, acc1);
        acc1 = fmaf(x1.z, a4.z, acc1); acc1 = fmaf(x1.w, a4.w, acc1);
        acc2 = fmaf(x2.x, a4.x, acc2); acc2 = fmaf(x2.y, a4.y, acc2);
        acc2 = fmaf(x2.z, a4.z, acc2); acc2 = fmaf(x2.w, a4.w, acc2);
    }
    float bl0 = bs[lane], bl1 = bs[lane + 16], bl2 = bs[lane + 32];
    float smx = gsum(acc0 * acc0 + acc1 * acc1 + acc2 * acc2);
    float xyr = gsum(acc0 * bl0 + acc1 * bl1 + acc2 * bl2);
    float bn2 = gsum(bl0 * bl0 + bl1 * bl1 + bl2 * bl2);

    float mxnr = sqrtf(smx);
    float mxn = fmaxf(mxnr, F_EPS);
    float tt = fast_tanh(__fdividef(mxn, xn) * fast_atanh(xn));
    float sc = __fdividef(tt, mxn);
    float rn = mxnr * sc;
    if (rn > MAXNORM) sc *= MAXNORM / fmaxf(rn, F_EPS);

    float bn  = fmaxf(sqrtf(bn2), F_EPS);
    float ebs = __fdividef(fast_tanh(bn), bn);
    float y2  = ebs * ebs * bn2;

    float x2v = sc * sc * smx;
    float xy = sc * ebs * xyr;
    float c1 = 1.0f + 2.0f * xy + y2;
    float c2 = 1.0f - x2v;
    float dn3 = 1.0f / fmaxf(1.0f + 2.0f * xy + x2v * y2, F_EPS);

    float s3 = dn3 * dn3 * (c1 * c1 * sc * sc * smx
                            + 2.0f * c1 * c2 * sc * ebs * xyr
                            + c2 * c2 * ebs * ebs * bn2);
    float nrm3 = sqrtf(s3);
    float fp = (nrm3 > MAXNORM) ? (MAXNORM / fmaxf(nrm3, F_EPS)) : 1.0f;

    float CA = c1 * sc * dn3 * fp;
    float CB = c2 * ebs * dn3 * fp;

    if (act) {
        float* orow = out + (size_t)i * D;
        orow[lane]      = fmaf(CA, acc0, CB * bl0);
        orow[lane + 16] = fmaf(CA, acc1, CB * bl1);
        orow[lane + 32] = fmaf(CA, acc2, CB * bl2);
    }
}

// ---------- fallback path (atomic scatter + standalone node) ----------
__global__ void k_init_atomic(float* __restrict__ den, float* __restrict__ num, int n)
{
    int i = blockIdx.x * blockDim.x + threadIdx.x;
    if (i >= n) return;
    den[i] = 0.0f;
    float4* nr = reinterpret_cast<float4*>(num) + (size_t)i * DQ;
    float4 z = make_float4(0.f, 0.f, 0.f, 0.f);
#pragma unroll
    for (int q = 0; q < DQ; ++q) nr[q] = z;
}

__global__ void k_edge_atomic(const float* __restrict__ x, const float* __restrict__ gam,
                              const int* __restrict__ src, const int* __restrict__ dst,
                              const float* __restrict__ w,
                              float* __restrict__ num, float* __restrict__ den, int E)
{
    long long t = (long long)blockIdx.x * blockDim.x + threadIdx.x;
    int e = (int)(t / DQ);
    if (e >= E) return;
    int part = (int)(t % DQ);
    int s = src[e];
    int d = dst[e];
    float we = w[e];
    float g  = gam[s];
    float4 xv = reinterpret_cast<const float4*>(x)[(size_t)s * DQ + part];
    float c = we * g;
    float* np_ = num + (size_t)d * D + part * 4;
    atomicAdd(np_ + 0, c * xv.x);
    atomicAdd(np_ + 1, c * xv.y);
    atomicAdd(np_ + 2, c * xv.z);
    atomicAdd(np_ + 3, c * xv.w);
    if (part == 0) atomicAdd(den + d, fabsf(we) * (g - 1.0f));
}

__global__ __launch_bounds__(256) void k_node_fb(
    float* __restrict__ out,
    const float* __restrict__ den,
    const float* __restrict__ h_init,
    const float* __restrict__ Wm,
    const float* __restrict__ bias, int n)
{
    __shared__ float Ws[D * WSTR];
    __shared__ float bs[D];
    __shared__ float aLds[NPB][WSTR];
    int t = threadIdx.x;
    for (int k = t; k < D * D; k += 256) Ws[(k / D) * WSTR + (k % D)] = Wm[k];
    if (t < D) bs[t] = bias[t];
    __syncthreads();

    int grp = t >> 4;
    int lane = t & 15;
    int i = blockIdx.x * NPB + grp;
    bool act = (i < n);

    auto gsum = [](float v) {
        v += __shfl_xor(v, 1, 16);
        v += __shfl_xor(v, 2, 16);
        v += __shfl_xor(v, 4, 16);
        v += __shfl_xor(v, 8, 16);
        return v;
    };
    auto hmp_scale = [](float s) {
        float nrm = sqrtf(s);
        float ncl = fmaxf(nrm, F_EPS);
        float m = fminf(ncl, 1.0f - 1e-7f);
        float sc = __fdividef(__fdividef(m, ncl),
                              1.0f + sqrtf(fmaxf(1.0f - m * m, 0.0f)));
        float rn = nrm * sc;
        if (rn > MAXNORM) sc *= MAXNORM / fmaxf(rn, F_EPS);
        return sc;
    };

    float a0 = 0.f, a1 = 0.f, a2 = 0.f;
    if (act) {
        float dinv = 1.0f / clampabs(den[i]);
        const float* nr = out + (size_t)i * D;
        a0 = nr[lane] * dinv;
        a1 = nr[lane + 16] * dinv;
        a2 = nr[lane + 32] * dinv;
    }
    float s1 = gsum(a0 * a0 + a1 * a1 + a2 * a2);
    float sc1 = hmp_scale(s1);
    a0 *= sc1; a1 *= sc1; a2 *= sc1;
    float sa = s1 * sc1 * sc1;

    float s2, sc2;
    {
        float b0 = 0.f, b1 = 0.f, b2 = 0.f;
        if (act) {
            const float* hr = h_init + (size_t)i * D;
            b0 = hr[lane];
            b1 = hr[lane + 16];
            b2 = hr[lane + 32];
        }
        float sb = gsum(b0 * b0 + b1 * b1 + b2 * b2);
        float ga = 2.0f / fmaxf(1.0f - sa, F_EPS);
        float gb = 2.0f / fmaxf(1.0f - sb, F_EPS);
        const float wa = 0.9f, wb = 0.1f;
        float dinv = 1.0f / clampabs(wa * (ga - 1.0f) + wb * (gb - 1.0f));
        float ca = wa * ga * dinv, cb = wb * gb * dinv;
        a0 = ca * a0 + cb * b0;
        a1 = ca * a1 + cb * b1;
        a2 = ca * a2 + cb * b2;
        s2 = gsum(a0 * a0 + a1 * a1 + a2 * a2);
        sc2 = hmp_scale(s2);
        a0 *= sc2; a1 *= sc2; a2 *= sc2;
    }
    float xn = fmaxf(sqrtf(s2) * sc2, F_EPS);

    aLds[grp][lane]      = a0;
    aLds[grp][lane + 16] = a1;
    aLds[grp][lane + 32] = a2;
    __syncthreads();

    const float4* av4 = reinterpret_cast<const float4*>(&aLds[grp][0]);
    const float4* w04 = reinterpret_cast<const float4*>(&Ws[lane * WSTR]);
    const float4* w14 = reinterpret_cast<const float4*>(&Ws[(lane + 16) * WSTR]);
    const float4* w24 = reinterpret_cast<const float4*>(&Ws[(lane + 32) * WSTR]);
    float acc0 = 0.f, acc1 = 0.f, acc2 = 0.f;
#pragma unroll
    for (int kq = 0; kq < DQ; ++kq) {
        float4 a4 = av4[kq];
        float4 x0 = w04[kq];
        float4 x1 = w14[kq];
        float4 x2 = w24[kq];
        acc0 = fmaf(x0.x, a4.x, acc0); acc0 = fmaf(x0.y, a4.y, acc0);
        acc0 = fmaf(x0.z, a4.z, acc0); acc0 = fmaf(x0.w, a4.w, acc0);
        acc1 = fmaf(x1.x, a4.x, acc1); acc1 = fmaf(x1.y, a4.y, acc1);
        acc1 = fmaf(x1.z, a4.z, acc1); acc1 = fmaf(x1.w, a4.w, acc1);
        acc2 = fmaf(x2.x, a4.x, acc2); acc2 = fmaf(x2.y, a4.y, acc2);
        acc2 = fmaf(x2.z, a4.z, acc2); acc2 = fmaf(x2.w, a4.w, acc2);
    }
    float bl0 = bs[lane], bl1 = bs[lane + 16], bl2 = bs[lane + 32];
    float smx = gsum(acc0 * acc0 + acc1 * acc1 + acc2 * acc2);
    float xyr = gsum(acc0 * bl0 + acc1 * bl1 + acc2 * bl2);
    float bn2 = gsum(bl0 * bl0 + bl1 * bl1 + bl2 * bl2);

    float mxnr = sqrtf(smx);
    float mxn = fmaxf(mxnr, F_EPS);
    float tt = fast_tanh(__fdividef(mxn, xn) * fast_atanh(xn));
    float sc = __fdividef(tt, mxn);
    float rn = mxnr * sc;
    if (rn > MAXNORM) sc *= MAXNORM / fmaxf(rn, F_EPS);

    float bn  = fmaxf(sqrtf(bn2), F_EPS);
    float ebs = __fdividef(fast_tanh(bn), bn);
    float y2  = ebs * ebs * bn2;

    float x2v = sc * sc * smx;
    float xy = sc * ebs * xyr;
    float c1 = 1.0f + 2.0f * xy + y2;
    float c2 = 1.0f - x2v;
    float dn3 = 1.0f / fmaxf(1.0f + 2.0f * xy + x2v * y2, F_EPS);

    float s3 = dn3 * dn3 * (c1 * c1 * sc * sc * smx
                            + 2.0f * c1 * c2 * sc * ebs * xyr
                            + c2 * c2 * ebs * ebs * bn2);
    float nrm3 = sqrtf(s3);
    float fp = (nrm3 > MAXNORM) ? (MAXNORM / fmaxf(nrm3, F_EPS)) : 1.0f;

    float CA = c1 * sc * dn3 * fp;
    float CB = c2 * ebs * dn3 * fp;

    if (act) {
        float* orow = out + (size_t)i * D;
        orow[lane]      = fmaf(CA, acc0, CB * bl0);
        orow[lane + 16] = fmaf(CA, acc1, CB * bl1);
        orow[lane + 32] = fmaf(CA, acc2, CB * bl2);
    }
}

extern "C" void kernel_launch(void* const* d_in, const int* in_sizes, int n_in,
                              void* d_out, int out_size, void* d_ws, size_t ws_size,
                              hipStream_t stream)
{
    const float* x      = (const float*)d_in[0];
    const float* h_init = (const float*)d_in[1];
    const float* edge_w = (const float*)d_in[2];
    const float* W      = (const float*)d_in[3];
    const float* bias   = (const float*)d_in[4];
    const int*   esrc   = (const int*)d_in[5];
    const int*   edst   = (const int*)d_in[6];
    float* out = (float*)d_out;

    int n = in_sizes[0] / D;
    int E = in_sizes[2];
    int nb = (n + SPAN - 1) >> SHIFT;

    // ws layout
    char* p = (char*)d_ws;
    float* gam    = (float*)p;             p += (size_t)n * 4;
    float* den    = (float*)p;             p += (size_t)n * 4;
    int*   ghist  = (int*)p;               p += (size_t)nb * 4;
    int*   gstart = (int*)p;               p += (size_t)(nb + 1) * 4;
    int*   gcur   = (int*)p;               p += (size_t)nb * 4;
    int*   starts = (int*)p;               p += (size_t)(n + 1) * 4;
    p = (char*)(((uintptr_t)p + 127) & ~(uintptr_t)127);  // align 128
    int2*  seg    = (int2*)p;              p += (size_t)E * 8;
    int2*  seg2   = (int2*)p;              p += (size_t)E * 8;
    size_t need1 = (size_t)(p - (char*)d_ws);
    ushort4* ybf = (ushort4*)seg;          // aliases seg (dead after k_sortb)
    bool ybf_fits = ((size_t)E * 8 >= (size_t)n * YROW * 8);

    k_gamma<<<(n + 255) / 256, 256, 0, stream>>>(x, gam, ghist, n, nb);

    bool shape_ok = (nb <= 1024) && (n < (1 << 24));
    if (shape_ok && ybf_fits && need1 <= ws_size) {
        int pb = (E + PCH - 1) / PCH;
        k_hist<<<pb, PTH, 0, stream>>>(edst, ghist, E, nb);
        k_scanb<<<1, 1024, 0, stream>>>(ghist, gstart, gcur, nb, E);
        k_part<<<pb, PTH, 0, stream>>>(esrc, edst, edge_w, gcur, seg, E, nb);
        k_sortb<<<nb, 256, 0, stream>>>(seg, gstart, starts, seg2, n, E);
        long long pt = (long long)n * YROW;
        k_prep<<<(int)((pt + 255) / 256), 256, 0, stream>>>(x, gam, ybf, n);
        k_fuse<<<(n + NPB - 1) / NPB, 256, 0, stream>>>(
            ybf, starts, seg2, h_init, W, bias, out, n, E);
    } else {
        k_init_atomic<<<(n + 255) / 256, 256, 0, stream>>>(den, out, n);
        long long tot = (long long)E * DQ;
        k_edge_atomic<<<(int)((tot + 255) / 256), 256, 0, stream>>>(x, gam, esrc, edst, edge_w, out, den, E);
        k_node_fb<<<(n + NPB - 1) / NPB, 256, 0, stream>>>(out, den, h_init, W, bias, n);
    }
}

// Round 19
// 143.980 us; speedup vs baseline: 1.0046x; 1.0046x over previous
//
#include <hip/hip_runtime.h>
#include <math.h>

#define D  48
#define DQ 12        // D/4
#define SPAN 128     // nodes per bucket
#define SHIFT 7      // log2(SPAN)
#define PCH  8192    // edges per hist/partition block
#define PTH  512     // threads for hist/part
#define NPB  16      // nodes per k_fuse block (16 threads/node)
#define WSTR 52      // LDS row stride (16B-aligned, low-conflict float4 reads)
#define YROW 16      // ybf row: 12 x ushort4 bf16(g*x) + slot12 (g-1 fp32) + pad to 128B

constexpr float F_EPS   = 1e-15f;
constexpr float MAXNORM = 1.0f - 1e-5f;

__device__ __forceinline__ float clampabs(float x) {
    return (x >= 0.0f) ? fmaxf(x, 1e-10f) : fminf(x, -1e-10f);
}

__device__ __forceinline__ unsigned short f2bf(float f) {
    unsigned u = __float_as_uint(f);
    u += 0x7FFFu + ((u >> 16) & 1u);
    return (unsigned short)(u >> 16);
}

__device__ __forceinline__ float bf2f(unsigned short u) {
    return __uint_as_float(((unsigned)u) << 16);
}

__device__ __forceinline__ float gm1f(ushort4 a) {   // fp32 packed in .x/.y
    return __uint_as_float((unsigned)a.x | ((unsigned)a.y << 16));
}

// fast tanh for x>=0 via hw exp (overflow-safe); fast atanh for 0<=x<1
__device__ __forceinline__ float fast_tanh(float x) {
    float e = __expf(2.0f * x);
    return 1.0f - __fdividef(2.0f, e + 1.0f);
}
__device__ __forceinline__ float fast_atanh(float x) {
    x = fminf(x, 1.0f - 1e-7f);
    return 0.5f * __logf(__fdividef(1.0f + x, 1.0f - x));
}

// ---------- per-node gamma + zero bucket histogram ----------
__global__ void k_gamma(const float* __restrict__ x, float* __restrict__ gam,
                        int* __restrict__ ghist, int n, int nb)
{
    int i = blockIdx.x * blockDim.x + threadIdx.x;
    if (i < nb) ghist[i] = 0;
    if (i >= n) return;
    const float4* xr = reinterpret_cast<const float4*>(x) + (size_t)i * DQ;
    float s = 0.0f;
#pragma unroll
    for (int q = 0; q < DQ; ++q) {
        float4 v = xr[q];
        s += v.x * v.x + v.y * v.y + v.z * v.z + v.w * v.w;
    }
    gam[i] = 2.0f / fmaxf(1.0f - s, F_EPS);
}

// ---------- bucket histogram (LDS-staged) ----------
__global__ __launch_bounds__(PTH) void k_hist(const int* __restrict__ dst,
                                              int* __restrict__ ghist, int E, int nb)
{
    __shared__ int h[1024];
    int t = threadIdx.x;
    for (int i = t; i < 1024; i += PTH) h[i] = 0;
    __syncthreads();
    int base = blockIdx.x * PCH;
#pragma unroll 4
    for (int k = 0; k < PCH / PTH; ++k) {
        int i = base + k * PTH + t;
        if (i < E) {
            unsigned b = ((unsigned)dst[i]) >> SHIFT;
            if (b < 1024u) atomicAdd(&h[b], 1);
        }
    }
    __syncthreads();
    for (int i = t; i < nb; i += PTH) {
        int c = h[i];
        if (c) atomicAdd(&ghist[i], c);
    }
}

// ---------- exclusive scan of bucket counts (single block, nb <= 1024) ----------
__global__ __launch_bounds__(1024) void k_scanb(const int* __restrict__ ghist,
                                                int* __restrict__ gstart,
                                                int* __restrict__ gcur, int nb, int E)
{
    __shared__ int sh[1024];
    int t = threadIdx.x;
    int v = (t < nb) ? ghist[t] : 0;
    sh[t] = v;
    __syncthreads();
    for (int off = 1; off < 1024; off <<= 1) {
        int a = sh[t];
        int b = (t >= off) ? sh[t - off] : 0;
        __syncthreads();
        sh[t] = a + b;
        __syncthreads();
    }
    if (t < nb) { int s = sh[t] - v; gstart[t] = s; gcur[t] = s; }
    if (t == 0) gstart[nb] = E;
}

// ---------- partition (pure streaming) ----------
__global__ __launch_bounds__(PTH) void k_part(const int* __restrict__ src,
                                              const int* __restrict__ dst,
                                              const float* __restrict__ w,
                                              int* __restrict__ gcur,
                                              int2* __restrict__ seg, int E, int nb)
{
    __shared__ int hist[1024];
    __shared__ int base_[1024];
    __shared__ int lcur[1024];
    int t = threadIdx.x;
    for (int i = t; i < 1024; i += PTH) { hist[i] = 0; base_[i] = 0; lcur[i] = 0; }
    __syncthreads();
    int b0 = blockIdx.x * PCH;
#pragma unroll 4
    for (int k = 0; k < PCH / PTH; ++k) {
        int i = b0 + k * PTH + t;
        if (i < E) {
            unsigned b = ((unsigned)dst[i]) >> SHIFT;
            if (b < 1024u) atomicAdd(&hist[b], 1);
        }
    }
    __syncthreads();
    for (int i = t; i < nb; i += PTH) {
        int c = hist[i];
        if (c) base_[i] = atomicAdd(&gcur[i], c);
    }
    __syncthreads();
#pragma unroll 4
    for (int k = 0; k < PCH / PTH; ++k) {
        int i = b0 + k * PTH + t;
        if (i < E) {
            int d = dst[i];
            unsigned b = ((unsigned)d) >> SHIFT;
            if (b < 1024u) {
                int pos = base_[b] + atomicAdd(&lcur[b], 1);
                if (pos >= 0 && pos < E) {
                    int2 r;
                    r.x = ((d & (SPAN - 1)) << 24) | (src[i] & 0xFFFFFF);
                    r.y = __float_as_int(w[i]);
                    seg[pos] = r;
                }
            }
        }
    }
}

// ---------- per-bucket LDS counting sort -> exact per-node order + starts ----------
__global__ __launch_bounds__(256) void k_sortb(
    const int2* __restrict__ seg, const int* __restrict__ gstart,
    int* __restrict__ starts, int2* __restrict__ seg2, int n, int E)
{
    __shared__ int hist[SPAN];
    __shared__ int sb[SPAN];
    __shared__ int cur[SPAN];
    int b = blockIdx.x;
    int t = threadIdx.x;
    if (b == 0 && t == 0) starts[n] = E;
    int segL = gstart[b], segR = gstart[b + 1];
    if (segL < 0) segL = 0;
    if (segR > E) segR = E;
    if (t < SPAN) hist[t] = 0;
    __syncthreads();
    {
        int j = segL + t;
        for (; j + 768 < segR; j += 1024) {
            unsigned d0 = ((unsigned)seg[j      ].x) >> 24;
            unsigned d1 = ((unsigned)seg[j + 256].x) >> 24;
            unsigned d2 = ((unsigned)seg[j + 512].x) >> 24;
            unsigned d3 = ((unsigned)seg[j + 768].x) >> 24;
            atomicAdd(&hist[d0], 1);
            atomicAdd(&hist[d1], 1);
            atomicAdd(&hist[d2], 1);
            atomicAdd(&hist[d3], 1);
        }
        for (; j < segR; j += 256) {
            unsigned dl = ((unsigned)seg[j].x) >> 24;
            atomicAdd(&hist[dl], 1);
        }
    }
    __syncthreads();
    if (t < SPAN) sb[t] = hist[t];
    __syncthreads();
    for (int off = 1; off < SPAN; off <<= 1) {
        int a = 0;
        if (t < SPAN) { a = sb[t]; if (t >= off) a += sb[t - off]; }
        __syncthreads();
        if (t < SPAN) sb[t] = a;
        __syncthreads();
    }
    if (t < SPAN) {
        int ls = sb[t] - hist[t];
        cur[t] = segL + ls;
        int node = b * SPAN + t;
        if (node < n) starts[node] = segL + ls;
    }
    __syncthreads();
    {
        int j = segL + t;
        for (; j + 768 < segR; j += 1024) {
            int2 r0 = seg[j      ];
            int2 r1 = seg[j + 256];
            int2 r2 = seg[j + 512];
            int2 r3 = seg[j + 768];
            int p0 = atomicAdd(&cur[((unsigned)r0.x) >> 24], 1);
            int p1 = atomicAdd(&cur[((unsigned)r1.x) >> 24], 1);
            int p2 = atomicAdd(&cur[((unsigned)r2.x) >> 24], 1);
            int p3 = atomicAdd(&cur[((unsigned)r3.x) >> 24], 1);
            if (p0 >= 0 && p0 < E) seg2[p0] = make_int2(r0.x & 0xFFFFFF, r0.y);
            if (p1 >= 0 && p1 < E) seg2[p1] = make_int2(r1.x & 0xFFFFFF, r1.y);
            if (p2 >= 0 && p2 < E) seg2[p2] = make_int2(r2.x & 0xFFFFFF, r2.y);
            if (p3 >= 0 && p3 < E) seg2[p3] = make_int2(r3.x & 0xFFFFFF, r3.y);
        }
        for (; j < segR; j += 256) {
            int2 r = seg[j];
            int pos = atomicAdd(&cur[((unsigned)r.x) >> 24], 1);
            if (pos >= 0 && pos < E) seg2[pos] = make_int2(r.x & 0xFFFFFF, r.y);
        }
    }
}

// ---------- k_prep: 128B-aligned ybf rows: 12x bf16(g*x) + fp32(g-1) + pad ----------
__global__ __launch_bounds__(256) void k_prep(const float* __restrict__ x,
                                              const float* __restrict__ gam,
                                              ushort4* __restrict__ ybf, int n)
{
    long long t = (long long)blockIdx.x * blockDim.x + threadIdx.x;
    int node = (int)(t / YROW);
    if (node >= n) return;
    int slot = (int)(t % YROW);
    float g = gam[node];
    ushort4 o;
    if (slot < 12) {
        float4 v = reinterpret_cast<const float4*>(x)[(size_t)node * DQ + slot];
        o.x = f2bf(v.x * g);
        o.y = f2bf(v.y * g);
        o.z = f2bf(v.z * g);
        o.w = f2bf(v.w * g);
    } else if (slot == 12) {
        unsigned u = __float_as_uint(g - 1.0f);
        o.x = (unsigned short)(u & 0xFFFFu);
        o.y = (unsigned short)(u >> 16);
        o.z = 0; o.w = 0;
    } else {
        o.x = 0; o.y = 0; o.z = 0; o.w = 0;   // pad
    }
    ybf[(size_t)node * YROW + slot] = o;
}

// ---------- fused gather + node math: 16 lanes per node, 8-wide gather ----------
// launch_bounds(256, 4): VGPR cap 128. The default heuristic allocated 32
// VGPRs (R16-R18 counters), which cannot hold 8 in-flight row loads
// (8 ushort4 + 8 int2 = 32 regs data alone) — the compiler serialized the
// gather pipeline to 1-2 outstanding loads. Trading occupancy (8->4 waves/
// SIMD) for true 8-deep MLP.
__global__ __launch_bounds__(256, 4) void k_fuse(
    const ushort4* __restrict__ ybf,
    const int* __restrict__ starts,
    const int2* __restrict__ srec,
    const float* __restrict__ h_init,
    const float* __restrict__ Wm,
    const float* __restrict__ bias,
    float* __restrict__ out, int n, int E)
{
    __shared__ float Ws[D * WSTR];
    __shared__ float bs[D];
    __shared__ float aLds[NPB][WSTR];
    int t = threadIdx.x;
    for (int k = t; k < D * D; k += 256) Ws[(k / D) * WSTR + (k % D)] = Wm[k];
    if (t < D) bs[t] = bias[t];

    int grp = t >> 4;
    int lane = t & 15;
    int i = blockIdx.x * NPB + grp;
    bool act = (i < n);

    auto gsum = [](float v) {
        v += __shfl_xor(v, 1, 16);
        v += __shfl_xor(v, 2, 16);
        v += __shfl_xor(v, 4, 16);
        v += __shfl_xor(v, 8, 16);
        return v;
    };
    auto hmp_scale = [](float s) {     // tanh(0.5*atanh(m))/m with project
        float nrm = sqrtf(s);
        float ncl = fmaxf(nrm, F_EPS);
        float m = fminf(ncl, 1.0f - 1e-7f);
        float sc = __fdividef(__fdividef(m, ncl),
                              1.0f + sqrtf(fmaxf(1.0f - m * m, 0.0f)));
        float rn = nrm * sc;
        if (rn > MAXNORM) sc *= MAXNORM / fmaxf(rn, F_EPS);
        return sc;
    };

    // ---- gather: lanes 0-11 num fragments; lanes 12-15 split den 4 ways
    int j0 = 0, j1 = 0;
    if (act) {
        j0 = starts[i]; j1 = starts[i + 1];
        if (j0 < 0) j0 = 0;
        if (j1 > E) j1 = E;
    }
    float4 acc = make_float4(0.f, 0.f, 0.f, 0.f);
    float dacc = 0.f;
    int j = j0;
    for (; j + 7 < j1; j += 8) {
        if (lane < 12) {
            int2 r0 = srec[j];
            int2 r1 = srec[j + 1];
            int2 r2 = srec[j + 2];
            int2 r3 = srec[j + 3];
            int2 r4 = srec[j + 4];
            int2 r5 = srec[j + 5];
            int2 r6 = srec[j + 6];
            int2 r7 = srec[j + 7];
            ushort4 a0 = ybf[(size_t)r0.x * YROW + lane];
            ushort4 a1 = ybf[(size_t)r1.x * YROW + lane];
            ushort4 a2 = ybf[(size_t)r2.x * YROW + lane];
            ushort4 a3 = ybf[(size_t)r3.x * YROW + lane];
            ushort4 a4 = ybf[(size_t)r4.x * YROW + lane];
            ushort4 a5 = ybf[(size_t)r5.x * YROW + lane];
            ushort4 a6 = ybf[(size_t)r6.x * YROW + lane];
            ushort4 a7 = ybf[(size_t)r7.x * YROW + lane];
            float w0 = __int_as_float(r0.y);
            float w1 = __int_as_float(r1.y);
            float w2 = __int_as_float(r2.y);
            float w3 = __int_as_float(r3.y);
            float w4 = __int_as_float(r4.y);
            float w5 = __int_as_float(r5.y);
            float w6 = __int_as_float(r6.y);
            float w7 = __int_as_float(r7.y);
            acc.x = fmaf(w0, bf2f(a0.x), acc.x);
            acc.y = fmaf(w0, bf2f(a0.y), acc.y);
            acc.z = fmaf(w0, bf2f(a0.z), acc.z);
            acc.w = fmaf(w0, bf2f(a0.w), acc.w);
            acc.x = fmaf(w1, bf2f(a1.x), acc.x);
            acc.y = fmaf(w1, bf2f(a1.y), acc.y);
            acc.z = fmaf(w1, bf2f(a1.z), acc.z);
            acc.w = fmaf(w1, bf2f(a1.w), acc.w);
            acc.x = fmaf(w2, bf2f(a2.x), acc.x);
            acc.y = fmaf(w2, bf2f(a2.y), acc.y);
            acc.z = fmaf(w2, bf2f(a2.z), acc.z);
            acc.w = fmaf(w2, bf2f(a2.w), acc.w);
            acc.x = fmaf(w3, bf2f(a3.x), acc.x);
            acc.y = fmaf(w3, bf2f(a3.y), acc.y);
            acc.z = fmaf(w3, bf2f(a3.z), acc.z);
            acc.w = fmaf(w3, bf2f(a3.w), acc.w);
            acc.x = fmaf(w4, bf2f(a4.x), acc.x);
            acc.y = fmaf(w4, bf2f(a4.y), acc.y);
            acc.z = fmaf(w4, bf2f(a4.z), acc.z);
            acc.w = fmaf(w4, bf2f(a4.w), acc.w);
            acc.x = fmaf(w5, bf2f(a5.x), acc.x);
            acc.y = fmaf(w5, bf2f(a5.y), acc.y);
            acc.z = fmaf(w5, bf2f(a5.z), acc.z);
            acc.w = fmaf(w5, bf2f(a5.w), acc.w);
            acc.x = fmaf(w6, bf2f(a6.x), acc.x);
            acc.y = fmaf(w6, bf2f(a6.y), acc.y);
            acc.z = fmaf(w6, bf2f(a6.z), acc.z);
            acc.w = fmaf(w6, bf2f(a6.w), acc.w);
            acc.x = fmaf(w7, bf2f(a7.x), acc.x);
            acc.y = fmaf(w7, bf2f(a7.y), acc.y);
            acc.z = fmaf(w7, bf2f(a7.z), acc.z);
            acc.w = fmaf(w7, bf2f(a7.w), acc.w);
        } else {
            int ll = lane - 12;
            int2 ra = srec[j + ll];
            int2 rb = srec[j + 4 + ll];
            ushort4 ga = ybf[(size_t)ra.x * YROW + 12];
            ushort4 gb = ybf[(size_t)rb.x * YROW + 12];
            dacc += fabsf(__int_as_float(ra.y)) * gm1f(ga)
                  + fabsf(__int_as_float(rb.y)) * gm1f(gb);
        }
    }
    // tail: lanes 0-11 num, lane 12 den
    for (; j < j1; ++j) {
        int2 r0 = srec[j];
        float w0 = __int_as_float(r0.y);
        if (lane < 12) {
            ushort4 a0 = ybf[(size_t)r0.x * YROW + lane];
            acc.x = fmaf(w0, bf2f(a0.x), acc.x);
            acc.y = fmaf(w0, bf2f(a0.y), acc.y);
            acc.z = fmaf(w0, bf2f(a0.z), acc.z);
            acc.w = fmaf(w0, bf2f(a0.w), acc.w);
        } else if (lane == 12) {
            ushort4 a0 = ybf[(size_t)r0.x * YROW + 12];
            dacc += fabsf(w0) * gm1f(a0);
        }
    }

    float dv = gsum(dacc);     // lanes 0-11 contribute 0; all lanes get den

    // redistribute num fragments (4p..4p+3) -> per-lane elems {l,l+16,l+32}
    if (lane < 12)
        reinterpret_cast<float4*>(&aLds[grp][0])[lane] = acc;
    __syncthreads();

    // ---- node math
    float dinv = 1.0f / clampabs(dv);
    float a0 = aLds[grp][lane]      * dinv;
    float a1 = aLds[grp][lane + 16] * dinv;
    float a2 = aLds[grp][lane + 32] * dinv;

    float s1 = gsum(a0 * a0 + a1 * a1 + a2 * a2);
    float sc1 = hmp_scale(s1);
    a0 *= sc1; a1 *= sc1; a2 *= sc1;
    float sa = s1 * sc1 * sc1;

    float s2, sc2;
    {
        float b0 = 0.f, b1 = 0.f, b2 = 0.f;
        if (act) {
            const float* hr = h_init + (size_t)i * D;
            b0 = hr[lane];
            b1 = hr[lane + 16];
            b2 = hr[lane + 32];
        }
        float sb = gsum(b0 * b0 + b1 * b1 + b2 * b2);
        float ga = 2.0f / fmaxf(1.0f - sa, F_EPS);
        float gb = 2.0f / fmaxf(1.0f - sb, F_EPS);
        const float wa = 0.9f, wb = 0.1f;
        float dinv2 = 1.0f / clampabs(wa * (ga - 1.0f) + wb * (gb - 1.0f));
        float ca = wa * ga * dinv2, cb = wb * gb * dinv2;
        a0 = ca * a0 + cb * b0;
        a1 = ca * a1 + cb * b1;
        a2 = ca * a2 + cb * b2;
        s2 = gsum(a0 * a0 + a1 * a1 + a2 * a2);
        sc2 = hmp_scale(s2);
        a0 *= sc2; a1 *= sc2; a2 *= sc2;
    }
    float xn = fmaxf(sqrtf(s2) * sc2, F_EPS);

    // restage projected a for the float4 matvec
    aLds[grp][lane]      = a0;
    aLds[grp][lane + 16] = a1;
    aLds[grp][lane + 32] = a2;
    __syncthreads();

    const float4* av4 = reinterpret_cast<const float4*>(&aLds[grp][0]);
    const float4* w04 = reinterpret_cast<const float4*>(&Ws[lane * WSTR]);
    const float4* w14 = reinterpret_cast<const float4*>(&Ws[(lane + 16) * WSTR]);
    const float4* w24 = reinterpret_cast<const float4*>(&Ws[(lane + 32) * WSTR]);
    float acc0 = 0.f, acc1 = 0.f, acc2 = 0.f;
#pragma unroll
    for (int kq = 0; kq < DQ; ++kq) {
        float4 a4 = av4[kq];
        float4 x0 = w04[kq];
        float4 x1 = w14[kq];
        float4 x2 = w24[kq];
        acc0 = fmaf(x0.x, a4.x, acc0); acc0 = fmaf(x0.y, a4.y, acc0);
        acc0 = fmaf(x0.z, a4.z, acc0); acc0 = fmaf(x0.w, a4.w, acc0);
        acc1 = fmaf(x1.x, a4.x, acc1); acc1 = fmaf(x1.y, a4.y, acc1);
        acc1 = fmaf(x1.z, a4.z, acc1); acc1 = fmaf(x1.w, a4.w, acc1);
        acc2 = fmaf(x2.x, a4.x, acc2); acc2 = fmaf(x2.y, a4.y, acc2);
        acc2 = fmaf(x2.z, a4.z, acc2); acc2 = fmaf(x2.w, a4.w, acc2);
    }
    float bl0 = bs[lane], bl1 = bs[lane + 16], bl2 = bs[lane + 32];
    float smx = gsum(acc0 * acc0 + acc1 * acc1 + acc2 * acc2);
    float xyr = gsum(acc0 * bl0 + acc1 * bl1 + acc2 * bl2);
    float bn2 = gsum(bl0 * bl0 + bl1 * bl1 + bl2 * bl2);

    float mxnr = sqrtf(smx);
    float mxn = fmaxf(mxnr, F_EPS);
    float tt = fast_tanh(__fdividef(mxn, xn) * fast_atanh(xn));
    float sc = __fdividef(tt, mxn);
    float rn = mxnr * sc;
    if (rn > MAXNORM) sc *= MAXNORM / fmaxf(rn, F_EPS);

    float bn  = fmaxf(sqrtf(bn2), F_EPS);
    float ebs = __fdividef(fast_tanh(bn), bn);
    float y2  = ebs * ebs * bn2;

    float x2v = sc * sc * smx;
    float xy = sc * ebs * xyr;
    float c1 = 1.0f + 2.0f * xy + y2;
    float c2 = 1.0f - x2v;
    float dn3 = 1.0f / fmaxf(1.0f + 2.0f * xy + x2v * y2, F_EPS);

    float s3 = dn3 * dn3 * (c1 * c1 * sc * sc * smx
                            + 2.0f * c1 * c2 * sc * ebs * xyr
                            + c2 * c2 * ebs * ebs * bn2);
    float nrm3 = sqrtf(s3);
    float fp = (nrm3 > MAXNORM) ? (MAXNORM / fmaxf(nrm3, F_EPS)) : 1.0f;

    float CA = c1 * sc * dn3 * fp;
    float CB = c2 * ebs * dn3 * fp;

    if (act) {
        float* orow = out + (size_t)i * D;
        orow[lane]      = fmaf(CA, acc0, CB * bl0);
        orow[lane + 16] = fmaf(CA, acc1, CB * bl1);
        orow[lane + 32] = fmaf(CA, acc2, CB * bl2);
    }
}

// ---------- fallback path (atomic scatter + standalone node) ----------
__global__ void k_init_atomic(float* __restrict__ den, float* __restrict__ num, int n)
{
    int i = blockIdx.x * blockDim.x + threadIdx.x;
    if (i >= n) return;
    den[i] = 0.0f;
    float4* nr = reinterpret_cast<float4*>(num) + (size_t)i * DQ;
    float4 z = make_float4(0.f, 0.f, 0.f, 0.f);
#pragma unroll
    for (int q = 0; q < DQ; ++q) nr[q] = z;
}

__global__ void k_edge_atomic(const float* __restrict__ x, const float* __restrict__ gam,
                              const int* __restrict__ src, const int* __restrict__ dst,
                              const float* __restrict__ w,
                              float* __restrict__ num, float* __restrict__ den, int E)
{
    long long t = (long long)blockIdx.x * blockDim.x + threadIdx.x;
    int e = (int)(t / DQ);
    if (e >= E) return;
    int part = (int)(t % DQ);
    int s = src[e];
    int d = dst[e];
    float we = w[e];
    float g  = gam[s];
    float4 xv = reinterpret_cast<const float4*>(x)[(size_t)s * DQ + part];
    float c = we * g;
    float* np_ = num + (size_t)d * D + part * 4;
    atomicAdd(np_ + 0, c * xv.x);
    atomicAdd(np_ + 1, c * xv.y);
    atomicAdd(np_ + 2, c * xv.z);
    atomicAdd(np_ + 3, c * xv.w);
    if (part == 0) atomicAdd(den + d, fabsf(we) * (g - 1.0f));
}

__global__ __launch_bounds__(256) void k_node_fb(
    float* __restrict__ out,
    const float* __restrict__ den,
    const float* __restrict__ h_init,
    const float* __restrict__ Wm,
    const float* __restrict__ bias, int n)
{
    __shared__ float Ws[D * WSTR];
    __shared__ float bs[D];
    __shared__ float aLds[NPB][WSTR];
    int t = threadIdx.x;
    for (int k = t; k < D * D; k += 256) Ws[(k / D) * WSTR + (k % D)] = Wm[k];
    if (t < D) bs[t] = bias[t];
    __syncthreads();

    int grp = t >> 4;
    int lane = t & 15;
    int i = blockIdx.x * NPB + grp;
    bool act = (i < n);

    auto gsum = [](float v) {
        v += __shfl_xor(v, 1, 16);
        v += __shfl_xor(v, 2, 16);
        v += __shfl_xor(v, 4, 16);
        v += __shfl_xor(v, 8, 16);
        return v;
    };
    auto hmp_scale = [](float s) {
        float nrm = sqrtf(s);
        float ncl = fmaxf(nrm, F_EPS);
        float m = fminf(ncl, 1.0f - 1e-7f);
        float sc = __fdividef(__fdividef(m, ncl),
                              1.0f + sqrtf(fmaxf(1.0f - m * m, 0.0f)));
        float rn = nrm * sc;
        if (rn > MAXNORM) sc *= MAXNORM / fmaxf(rn, F_EPS);
        return sc;
    };

    float a0 = 0.f, a1 = 0.f, a2 = 0.f;
    if (act) {
        float dinv = 1.0f / clampabs(den[i]);
        const float* nr = out + (size_t)i * D;
        a0 = nr[lane] * dinv;
        a1 = nr[lane + 16] * dinv;
        a2 = nr[lane + 32] * dinv;
    }
    float s1 = gsum(a0 * a0 + a1 * a1 + a2 * a2);
    float sc1 = hmp_scale(s1);
    a0 *= sc1; a1 *= sc1; a2 *= sc1;
    float sa = s1 * sc1 * sc1;

    float s2, sc2;
    {
        float b0 = 0.f, b1 = 0.f, b2 = 0.f;
        if (act) {
            const float* hr = h_init + (size_t)i * D;
            b0 = hr[lane];
            b1 = hr[lane + 16];
            b2 = hr[lane + 32];
        }
        float sb = gsum(b0 * b0 + b1 * b1 + b2 * b2);
        float ga = 2.0f / fmaxf(1.0f - sa, F_EPS);
        float gb = 2.0f / fmaxf(1.0f - sb, F_EPS);
        const float wa = 0.9f, wb = 0.1f;
        float dinv = 1.0f / clampabs(wa * (ga - 1.0f) + wb * (gb - 1.0f));
        float ca = wa * ga * dinv, cb = wb * gb * dinv;
        a0 = ca * a0 + cb * b0;
        a1 = ca * a1 + cb * b1;
        a2 = ca * a2 + cb * b2;
        s2 = gsum(a0 * a0 + a1 * a1 + a2 * a2);
        sc2 = hmp_scale(s2);
        a0 *= sc2; a1 *= sc2; a2 *= sc2;
    }
    float xn = fmaxf(sqrtf(s2) * sc2, F_EPS);

    aLds[grp][lane]      = a0;
    aLds[grp][lane + 16] = a1;
    aLds[grp][lane + 32] = a2;
    __syncthreads();

    const float4* av4 = reinterpret_cast<const float4*>(&aLds[grp][0]);
    const float4* w04 = reinterpret_cast<const float4*>(&Ws[lane * WSTR]);
    const float4* w14 = reinterpret_cast<const float4*>(&Ws[(lane + 16) * WSTR]);
    const float4* w24 = reinterpret_cast<const float4*>(&Ws[(lane + 32) * WSTR]);
    float acc0 = 0.f, acc1 = 0.f, acc2 = 0.f;
#pragma unroll
    for (int kq = 0; kq < DQ; ++kq) {
        float4 a4 = av4[kq];
        float4 x0 = w04[kq];
        float4 x1 = w14[kq];
        float4 x2 = w24[kq];
        acc0 = fmaf(x0.x, a4.x, acc0); acc0 = fmaf(x0.y, a4.y, acc0);
        acc0 = fmaf(x0.z, a4.z, acc0); acc0 = fmaf(x0.w, a4.w, acc0);
        acc1 = fmaf(x1.x, a4.x, acc1); acc1 = fmaf(x1.y, a4.y, acc1);
        acc1 = fmaf(x1.z, a4.z, acc1); acc1 = fmaf(x1.w, a4.w, acc1);
        acc2 = fmaf(x2.x, a4.x, acc2); acc2 = fmaf(x2.y, a4.y, acc2);
        acc2 = fmaf(x2.z, a4.z, acc2); acc2 = fmaf(x2.w, a4.w, acc2);
    }
    float bl0 = bs[lane], bl1 = bs[lane + 16], bl2 = bs[lane + 32];
    float smx = gsum(acc0 * acc0 + acc1 * acc1 + acc2 * acc2);
    float xyr = gsum(acc0 * bl0 + acc1 * bl1 + acc2 * bl2);
    float bn2 = gsum(bl0 * bl0 + bl1 * bl1 + bl2 * bl2);

    float mxnr = sqrtf(smx);
    float mxn = fmaxf(mxnr, F_EPS);
    float tt = fast_tanh(__fdividef(mxn, xn) * fast_atanh(xn));
    float sc = __fdividef(tt, mxn);
    float rn = mxnr * sc;
    if (rn > MAXNORM) sc *= MAXNORM / fmaxf(rn, F_EPS);

    float bn  = fmaxf(sqrtf(bn2), F_EPS);
    float ebs = __fdividef(fast_tanh(bn), bn);
    float y2  = ebs * ebs * bn2;

    float x2v = sc * sc * smx;
    float xy = sc * ebs * xyr;
    float c1 = 1.0f + 2.0f * xy + y2;
    float c2 = 1.0f - x2v;
    float dn3 = 1.0f / fmaxf(1.0f + 2.0f * xy + x2v * y2, F_EPS);

    float s3 = dn3 * dn3 * (c1 * c1 * sc * sc * smx
                            + 2.0f * c1 * c2 * sc * ebs * xyr
                            + c2 * c2 * ebs * ebs * bn2);
    float nrm3 = sqrtf(s3);
    float fp = (nrm3 > MAXNORM) ? (MAXNORM / fmaxf(nrm3, F_EPS)) : 1.0f;

    float CA = c1 * sc * dn3 * fp;
    float CB = c2 * ebs * dn3 * fp;

    if (act) {
        float* orow = out + (size_t)i * D;
        orow[lane]      = fmaf(CA, acc0, CB * bl0);
        orow[lane + 16] = fmaf(CA, acc1, CB * bl1);
        orow[lane + 32] = fmaf(CA, acc2, CB * bl2);
    }
}

extern "C" void kernel_launch(void* const* d_in, const int* in_sizes, int n_in,
                              void* d_out, int out_size, void* d_ws, size_t ws_size,
                              hipStream_t stream)
{
    const float* x      = (const float*)d_in[0];
    const float* h_init = (const float*)d_in[1];
    const float* edge_w = (const float*)d_in[2];
    const float* W      = (const float*)d_in[3];
    const float* bias   = (const float*)d_in[4];
    const int*   esrc   = (const int*)d_in[5];
    const int*   edst   = (const int*)d_in[6];
    float* out = (float*)d_out;

    int n = in_sizes[0] / D;
    int E = in_sizes[2];
    int nb = (n + SPAN - 1) >> SHIFT;

    // ws layout
    char* p = (char*)d_ws;
    float* gam    = (float*)p;             p += (size_t)n * 4;
    float* den    = (float*)p;             p += (size_t)n * 4;
    int*   ghist  = (int*)p;               p += (size_t)nb * 4;
    int*   gstart = (int*)p;               p += (size_t)(nb + 1) * 4;
    int*   gcur   = (int*)p;               p += (size_t)nb * 4;
    int*   starts = (int*)p;               p += (size_t)(n + 1) * 4;
    p = (char*)(((uintptr_t)p + 127) & ~(uintptr_t)127);  // align 128
    int2*  seg    = (int2*)p;              p += (size_t)E * 8;
    int2*  seg2   = (int2*)p;              p += (size_t)E * 8;
    size_t need1 = (size_t)(p - (char*)d_ws);
    ushort4* ybf = (ushort4*)seg;          // aliases seg (dead after k_sortb)
    bool ybf_fits = ((size_t)E * 8 >= (size_t)n * YROW * 8);

    k_gamma<<<(n + 255) / 256, 256, 0, stream>>>(x, gam, ghist, n, nb);

    bool shape_ok = (nb <= 1024) && (n < (1 << 24));
    if (shape_ok && ybf_fits && need1 <= ws_size) {
        int pb = (E + PCH - 1) / PCH;
        k_hist<<<pb, PTH, 0, stream>>>(edst, ghist, E, nb);
        k_scanb<<<1, 1024, 0, stream>>>(ghist, gstart, gcur, nb, E);
        k_part<<<pb, PTH, 0, stream>>>(esrc, edst, edge_w, gcur, seg, E, nb);
        k_sortb<<<nb, 256, 0, stream>>>(seg, gstart, starts, seg2, n, E);
        long long pt = (long long)n * YROW;
        k_prep<<<(int)((pt + 255) / 256), 256, 0, stream>>>(x, gam, ybf, n);
        k_fuse<<<(n + NPB - 1) / NPB, 256, 0, stream>>>(
            ybf, starts, seg2, h_init, W, bias, out, n, E);
    } else {
        k_init_atomic<<<(n + 255) / 256, 256, 0, stream>>>(den, out, n);
        long long tot = (long long)E * DQ;
        k_edge_atomic<<<(int)((tot + 255) / 256), 256, 0, stream>>>(x, gam, esrc, edst, edge_w, out, den, E);
        k_node_fb<<<(n + NPB - 1) / NPB, 256, 0, stream>>>(out, den, h_init, W, bias, n);
    }
}

// Round 20
// 141.679 us; speedup vs baseline: 1.0209x; 1.0162x over previous
//
#include <hip/hip_runtime.h>
#include <math.h>

#define D  48
#define DQ 12        // D/4
#define SPAN 128     // nodes per bucket
#define SHIFT 7      // log2(SPAN)
#define PCH  8192    // edges per partition block (burst size matters here)
#define HCH  2048    // edges per histogram block (no bursts -> small chunks)
#define PTH  512     // threads for hist/part
#define NPB  16      // nodes per k_fuse block (16 threads/node)
#define WSTR 52      // LDS row stride (16B-aligned, low-conflict float4 reads)
#define YROW 12      // ybf row: 12 x ushort4 bf16(g*x) = 96B (den lives in record)

constexpr float F_EPS   = 1e-15f;
constexpr float MAXNORM = 1.0f - 1e-5f;

__device__ __forceinline__ float clampabs(float x) {
    return (x >= 0.0f) ? fmaxf(x, 1e-10f) : fminf(x, -1e-10f);
}

__device__ __forceinline__ unsigned short f2bf(float f) {
    unsigned u = __float_as_uint(f);
    u += 0x7FFFu + ((u >> 16) & 1u);
    return (unsigned short)(u >> 16);
}

__device__ __forceinline__ float bf2f(unsigned short u) {
    return __uint_as_float(((unsigned)u) << 16);
}

// fast tanh for x>=0 via hw exp (overflow-safe); fast atanh for 0<=x<1
__device__ __forceinline__ float fast_tanh(float x) {
    float e = __expf(2.0f * x);
    return 1.0f - __fdividef(2.0f, e + 1.0f);
}
__device__ __forceinline__ float fast_atanh(float x) {
    x = fminf(x, 1.0f - 1e-7f);
    return 0.5f * __logf(__fdividef(1.0f + x, 1.0f - x));
}

// ---------- per-node gamma + zero bucket histogram ----------
__global__ void k_gamma(const float* __restrict__ x, float* __restrict__ gam,
                        int* __restrict__ ghist, int n, int nb)
{
    int i = blockIdx.x * blockDim.x + threadIdx.x;
    if (i < nb) ghist[i] = 0;
    if (i >= n) return;
    const float4* xr = reinterpret_cast<const float4*>(x) + (size_t)i * DQ;
    float s = 0.0f;
#pragma unroll
    for (int q = 0; q < DQ; ++q) {
        float4 v = xr[q];
        s += v.x * v.x + v.y * v.y + v.z * v.z + v.w * v.w;
    }
    gam[i] = 2.0f / fmaxf(1.0f - s, F_EPS);
}

// ---------- bucket histogram (LDS-staged, small chunks for parallelism) ----------
__global__ __launch_bounds__(PTH) void k_hist(const int* __restrict__ dst,
                                              int* __restrict__ ghist, int E, int nb)
{
    __shared__ int h[1024];
    int t = threadIdx.x;
    for (int i = t; i < 1024; i += PTH) h[i] = 0;
    __syncthreads();
    int base = blockIdx.x * HCH;
#pragma unroll
    for (int k = 0; k < HCH / PTH; ++k) {
        int i = base + k * PTH + t;
        if (i < E) {
            unsigned b = ((unsigned)dst[i]) >> SHIFT;
            if (b < 1024u) atomicAdd(&h[b], 1);
        }
    }
    __syncthreads();
    for (int i = t; i < nb; i += PTH) {
        int c = h[i];
        if (c) atomicAdd(&ghist[i], c);
    }
}

// ---------- exclusive scan of bucket counts (single block, nb <= 1024) ----------
__global__ __launch_bounds__(1024) void k_scanb(const int* __restrict__ ghist,
                                                int* __restrict__ gstart,
                                                int* __restrict__ gcur, int nb, int E)
{
    __shared__ int sh[1024];
    int t = threadIdx.x;
    int v = (t < nb) ? ghist[t] : 0;
    sh[t] = v;
    __syncthreads();
    for (int off = 1; off < 1024; off <<= 1) {
        int a = sh[t];
        int b = (t >= off) ? sh[t - off] : 0;
        __syncthreads();
        sh[t] = a + b;
        __syncthreads();
    }
    if (t < nb) { int s = sh[t] - v; gstart[t] = s; gcur[t] = s; }
    if (t == 0) gstart[nb] = E;
}

// ---------- partition: records carry bf16(w) and bf16(|w|(g-1)) ----------
__global__ __launch_bounds__(PTH) void k_part(const int* __restrict__ src,
                                              const int* __restrict__ dst,
                                              const float* __restrict__ w,
                                              const float* __restrict__ gam,
                                              int* __restrict__ gcur,
                                              int2* __restrict__ seg, int E, int nb)
{
    __shared__ int hist[1024];
    __shared__ int base_[1024];
    __shared__ int lcur[1024];
    int t = threadIdx.x;
    for (int i = t; i < 1024; i += PTH) { hist[i] = 0; base_[i] = 0; lcur[i] = 0; }
    __syncthreads();
    int b0 = blockIdx.x * PCH;
#pragma unroll 4
    for (int k = 0; k < PCH / PTH; ++k) {
        int i = b0 + k * PTH + t;
        if (i < E) {
            unsigned b = ((unsigned)dst[i]) >> SHIFT;
            if (b < 1024u) atomicAdd(&hist[b], 1);
        }
    }
    __syncthreads();
    for (int i = t; i < nb; i += PTH) {
        int c = hist[i];
        if (c) base_[i] = atomicAdd(&gcur[i], c);
    }
    __syncthreads();
#pragma unroll 4
    for (int k = 0; k < PCH / PTH; ++k) {
        int i = b0 + k * PTH + t;
        if (i < E) {
            int d = dst[i];
            unsigned b = ((unsigned)d) >> SHIFT;
            if (b < 1024u) {
                int s = src[i];
                float wv = w[i];
                float g  = gam[s];                 // hot 400KB array (L2-resident)
                unsigned short wb  = f2bf(wv);
                unsigned short wdb = f2bf(fabsf(wv) * (g - 1.0f));
                int pos = base_[b] + atomicAdd(&lcur[b], 1);
                if (pos >= 0 && pos < E) {
                    int2 r;
                    r.x = ((d & (SPAN - 1)) << 24) | (s & 0xFFFFFF);
                    r.y = ((unsigned)wb << 16) | wdb;
                    seg[pos] = r;
                }
            }
        }
    }
}

// ---------- per-bucket LDS counting sort -> exact per-node order + starts ----------
__global__ __launch_bounds__(256) void k_sortb(
    const int2* __restrict__ seg, const int* __restrict__ gstart,
    int* __restrict__ starts, int2* __restrict__ seg2, int n, int E)
{
    __shared__ int hist[SPAN];
    __shared__ int sb[SPAN];
    __shared__ int cur[SPAN];
    int b = blockIdx.x;
    int t = threadIdx.x;
    if (b == 0 && t == 0) starts[n] = E;
    int segL = gstart[b], segR = gstart[b + 1];
    if (segL < 0) segL = 0;
    if (segR > E) segR = E;
    if (t < SPAN) hist[t] = 0;
    __syncthreads();
    {
        int j = segL + t;
        for (; j + 768 < segR; j += 1024) {
            unsigned d0 = ((unsigned)seg[j      ].x) >> 24;
            unsigned d1 = ((unsigned)seg[j + 256].x) >> 24;
            unsigned d2 = ((unsigned)seg[j + 512].x) >> 24;
            unsigned d3 = ((unsigned)seg[j + 768].x) >> 24;
            atomicAdd(&hist[d0], 1);
            atomicAdd(&hist[d1], 1);
            atomicAdd(&hist[d2], 1);
            atomicAdd(&hist[d3], 1);
        }
        for (; j < segR; j += 256) {
            unsigned dl = ((unsigned)seg[j].x) >> 24;
            atomicAdd(&hist[dl], 1);
        }
    }
    __syncthreads();
    if (t < SPAN) sb[t] = hist[t];
    __syncthreads();
    for (int off = 1; off < SPAN; off <<= 1) {
        int a = 0;
        if (t < SPAN) { a = sb[t]; if (t >= off) a += sb[t - off]; }
        __syncthreads();
        if (t < SPAN) sb[t] = a;
        __syncthreads();
    }
    if (t < SPAN) {
        int ls = sb[t] - hist[t];
        cur[t] = segL + ls;
        int node = b * SPAN + t;
        if (node < n) starts[node] = segL + ls;
    }
    __syncthreads();
    {
        int j = segL + t;
        for (; j + 768 < segR; j += 1024) {
            int2 r0 = seg[j      ];
            int2 r1 = seg[j + 256];
            int2 r2 = seg[j + 512];
            int2 r3 = seg[j + 768];
            int p0 = atomicAdd(&cur[((unsigned)r0.x) >> 24], 1);
            int p1 = atomicAdd(&cur[((unsigned)r1.x) >> 24], 1);
            int p2 = atomicAdd(&cur[((unsigned)r2.x) >> 24], 1);
            int p3 = atomicAdd(&cur[((unsigned)r3.x) >> 24], 1);
            if (p0 >= 0 && p0 < E) seg2[p0] = make_int2(r0.x & 0xFFFFFF, r0.y);
            if (p1 >= 0 && p1 < E) seg2[p1] = make_int2(r1.x & 0xFFFFFF, r1.y);
            if (p2 >= 0 && p2 < E) seg2[p2] = make_int2(r2.x & 0xFFFFFF, r2.y);
            if (p3 >= 0 && p3 < E) seg2[p3] = make_int2(r3.x & 0xFFFFFF, r3.y);
        }
        for (; j < segR; j += 256) {
            int2 r = seg[j];
            int pos = atomicAdd(&cur[((unsigned)r.x) >> 24], 1);
            if (pos >= 0 && pos < E) seg2[pos] = make_int2(r.x & 0xFFFFFF, r.y);
        }
    }
}

// ---------- k_prep: 96B ybf rows: 12x ushort4 of bf16(g*x) ----------
__global__ __launch_bounds__(256) void k_prep(const float* __restrict__ x,
                                              const float* __restrict__ gam,
                                              ushort4* __restrict__ ybf, int n)
{
    long long t = (long long)blockIdx.x * blockDim.x + threadIdx.x;
    int node = (int)(t / YROW);
    if (node >= n) return;
    int slot = (int)(t % YROW);
    float g = gam[node];
    float4 v = reinterpret_cast<const float4*>(x)[(size_t)node * DQ + slot];
    ushort4 o;
    o.x = f2bf(v.x * g);
    o.y = f2bf(v.y * g);
    o.z = f2bf(v.z * g);
    o.w = f2bf(v.w * g);
    ybf[(size_t)node * YROW + slot] = o;
}

// ---------- fused gather + node math: 16 lanes/node, 4-wide, den from record ----------
__global__ __launch_bounds__(256) void k_fuse(
    const ushort4* __restrict__ ybf,
    const int* __restrict__ starts,
    const int2* __restrict__ srec,
    const float* __restrict__ h_init,
    const float* __restrict__ Wm,
    const float* __restrict__ bias,
    float* __restrict__ out, int n, int E)
{
    __shared__ float Ws[D * WSTR];
    __shared__ float bs[D];
    __shared__ float aLds[NPB][WSTR];
    int t = threadIdx.x;
    for (int k = t; k < D * D; k += 256) Ws[(k / D) * WSTR + (k % D)] = Wm[k];
    if (t < D) bs[t] = bias[t];

    int grp = t >> 4;
    int lane = t & 15;
    int i = blockIdx.x * NPB + grp;
    bool act = (i < n);

    auto gsum = [](float v) {
        v += __shfl_xor(v, 1, 16);
        v += __shfl_xor(v, 2, 16);
        v += __shfl_xor(v, 4, 16);
        v += __shfl_xor(v, 8, 16);
        return v;
    };
    auto hmp_scale = [](float s) {     // tanh(0.5*atanh(m))/m with project
        float nrm = sqrtf(s);
        float ncl = fmaxf(nrm, F_EPS);
        float m = fminf(ncl, 1.0f - 1e-7f);
        float sc = __fdividef(__fdividef(m, ncl),
                              1.0f + sqrtf(fmaxf(1.0f - m * m, 0.0f)));
        float rn = nrm * sc;
        if (rn > MAXNORM) sc *= MAXNORM / fmaxf(rn, F_EPS);
        return sc;
    };

    // ---- gather: uniform across lanes; lanes 12-15 duplicate slots 0-3
    // (same-line loads, coalesced) and their acc is discarded. Every lane
    // sees every record (broadcast load) so dacc is complete per-lane.
    int j0 = 0, j1 = 0;
    if (act) {
        j0 = starts[i]; j1 = starts[i + 1];
        if (j0 < 0) j0 = 0;
        if (j1 > E) j1 = E;
    }
    int pp = (lane < 12) ? lane : (lane - 12);
    float4 acc = make_float4(0.f, 0.f, 0.f, 0.f);
    float dacc = 0.f;
    int j = j0;
    for (; j + 3 < j1; j += 4) {
        int2 r0 = srec[j];
        int2 r1 = srec[j + 1];
        int2 r2 = srec[j + 2];
        int2 r3 = srec[j + 3];
        ushort4 a0 = ybf[(size_t)r0.x * YROW + pp];
        ushort4 a1 = ybf[(size_t)r1.x * YROW + pp];
        ushort4 a2 = ybf[(size_t)r2.x * YROW + pp];
        ushort4 a3 = ybf[(size_t)r3.x * YROW + pp];
        float w0 = bf2f((unsigned short)(((unsigned)r0.y) >> 16));
        float w1 = bf2f((unsigned short)(((unsigned)r1.y) >> 16));
        float w2 = bf2f((unsigned short)(((unsigned)r2.y) >> 16));
        float w3 = bf2f((unsigned short)(((unsigned)r3.y) >> 16));
        acc.x = fmaf(w0, bf2f(a0.x), acc.x);
        acc.y = fmaf(w0, bf2f(a0.y), acc.y);
        acc.z = fmaf(w0, bf2f(a0.z), acc.z);
        acc.w = fmaf(w0, bf2f(a0.w), acc.w);
        acc.x = fmaf(w1, bf2f(a1.x), acc.x);
        acc.y = fmaf(w1, bf2f(a1.y), acc.y);
        acc.z = fmaf(w1, bf2f(a1.z), acc.z);
        acc.w = fmaf(w1, bf2f(a1.w), acc.w);
        acc.x = fmaf(w2, bf2f(a2.x), acc.x);
        acc.y = fmaf(w2, bf2f(a2.y), acc.y);
        acc.z = fmaf(w2, bf2f(a2.z), acc.z);
        acc.w = fmaf(w2, bf2f(a2.w), acc.w);
        acc.x = fmaf(w3, bf2f(a3.x), acc.x);
        acc.y = fmaf(w3, bf2f(a3.y), acc.y);
        acc.z = fmaf(w3, bf2f(a3.z), acc.z);
        acc.w = fmaf(w3, bf2f(a3.w), acc.w);
        dacc += bf2f((unsigned short)(((unsigned)r0.y) & 0xFFFF))
              + bf2f((unsigned short)(((unsigned)r1.y) & 0xFFFF))
              + bf2f((unsigned short)(((unsigned)r2.y) & 0xFFFF))
              + bf2f((unsigned short)(((unsigned)r3.y) & 0xFFFF));
    }
    for (; j < j1; ++j) {
        int2 r0 = srec[j];
        ushort4 a0 = ybf[(size_t)r0.x * YROW + pp];
        float w0 = bf2f((unsigned short)(((unsigned)r0.y) >> 16));
        acc.x = fmaf(w0, bf2f(a0.x), acc.x);
        acc.y = fmaf(w0, bf2f(a0.y), acc.y);
        acc.z = fmaf(w0, bf2f(a0.z), acc.z);
        acc.w = fmaf(w0, bf2f(a0.w), acc.w);
        dacc += bf2f((unsigned short)(((unsigned)r0.y) & 0xFFFF));
    }
    float dv = dacc;   // identical in every lane of the group

    // redistribute num fragments (4p..4p+3) -> per-lane elems {l,l+16,l+32}
    if (lane < 12)
        reinterpret_cast<float4*>(&aLds[grp][0])[lane] = acc;
    __syncthreads();

    // ---- node math
    float dinv = 1.0f / clampabs(dv);
    float a0 = aLds[grp][lane]      * dinv;
    float a1 = aLds[grp][lane + 16] * dinv;
    float a2 = aLds[grp][lane + 32] * dinv;

    float s1 = gsum(a0 * a0 + a1 * a1 + a2 * a2);
    float sc1 = hmp_scale(s1);
    a0 *= sc1; a1 *= sc1; a2 *= sc1;
    float sa = s1 * sc1 * sc1;

    float s2, sc2;
    {
        float b0 = 0.f, b1 = 0.f, b2 = 0.f;
        if (act) {
            const float* hr = h_init + (size_t)i * D;
            b0 = hr[lane];
            b1 = hr[lane + 16];
            b2 = hr[lane + 32];
        }
        float sb = gsum(b0 * b0 + b1 * b1 + b2 * b2);
        float ga = 2.0f / fmaxf(1.0f - sa, F_EPS);
        float gb = 2.0f / fmaxf(1.0f - sb, F_EPS);
        const float wa = 0.9f, wb = 0.1f;
        float dinv2 = 1.0f / clampabs(wa * (ga - 1.0f) + wb * (gb - 1.0f));
        float ca = wa * ga * dinv2, cb = wb * gb * dinv2;
        a0 = ca * a0 + cb * b0;
        a1 = ca * a1 + cb * b1;
        a2 = ca * a2 + cb * b2;
        s2 = gsum(a0 * a0 + a1 * a1 + a2 * a2);
        sc2 = hmp_scale(s2);
        a0 *= sc2; a1 *= sc2; a2 *= sc2;
    }
    float xn = fmaxf(sqrtf(s2) * sc2, F_EPS);

    // restage projected a for the float4 matvec
    aLds[grp][lane]      = a0;
    aLds[grp][lane + 16] = a1;
    aLds[grp][lane + 32] = a2;
    __syncthreads();

    const float4* av4 = reinterpret_cast<const float4*>(&aLds[grp][0]);
    const float4* w04 = reinterpret_cast<const float4*>(&Ws[lane * WSTR]);
    const float4* w14 = reinterpret_cast<const float4*>(&Ws[(lane + 16) * WSTR]);
    const float4* w24 = reinterpret_cast<const float4*>(&Ws[(lane + 32) * WSTR]);
    float acc0 = 0.f, acc1 = 0.f, acc2 = 0.f;
#pragma unroll
    for (int kq = 0; kq < DQ; ++kq) {
        float4 a4 = av4[kq];
        float4 x0 = w04[kq];
        float4 x1 = w14[kq];
        float4 x2 = w24[kq];
        acc0 = fmaf(x0.x, a4.x, acc0); acc0 = fmaf(x0.y, a4.y, acc0);
        acc0 = fmaf(x0.z, a4.z, acc0); acc0 = fmaf(x0.w, a4.w, acc0);
        acc1 = fmaf(x1.x, a4.x, acc1); acc1 = fmaf(x1.y, a4.y, acc1);
        acc1 = fmaf(x1.z, a4.z, acc1); acc1 = fmaf(x1.w, a4.w, acc1);
        acc2 = fmaf(x2.x, a4.x, acc2); acc2 = fmaf(x2.y, a4.y, acc2);
        acc2 = fmaf(x2.z, a4.z, acc2); acc2 = fmaf(x2.w, a4.w, acc2);
    }
    float bl0 = bs[lane], bl1 = bs[lane + 16], bl2 = bs[lane + 32];
    float smx = gsum(acc0 * acc0 + acc1 * acc1 + acc2 * acc2);
    float xyr = gsum(acc0 * bl0 + acc1 * bl1 + acc2 * bl2);
    float bn2 = gsum(bl0 * bl0 + bl1 * bl1 + bl2 * bl2);

    float mxnr = sqrtf(smx);
    float mxn = fmaxf(mxnr, F_EPS);
    float tt = fast_tanh(__fdividef(mxn, xn) * fast_atanh(xn));
    float sc = __fdividef(tt, mxn);
    float rn = mxnr * sc;
    if (rn > MAXNORM) sc *= MAXNORM / fmaxf(rn, F_EPS);

    float bn  = fmaxf(sqrtf(bn2), F_EPS);
    float ebs = __fdividef(fast_tanh(bn), bn);
    float y2  = ebs * ebs * bn2;

    float x2v = sc * sc * smx;
    float xy = sc * ebs * xyr;
    float c1 = 1.0f + 2.0f * xy + y2;
    float c2 = 1.0f - x2v;
    float dn3 = 1.0f / fmaxf(1.0f + 2.0f * xy + x2v * y2, F_EPS);

    float s3 = dn3 * dn3 * (c1 * c1 * sc * sc * smx
                            + 2.0f * c1 * c2 * sc * ebs * xyr
                            + c2 * c2 * ebs * ebs * bn2);
    float nrm3 = sqrtf(s3);
    float fp = (nrm3 > MAXNORM) ? (MAXNORM / fmaxf(nrm3, F_EPS)) : 1.0f;

    float CA = c1 * sc * dn3 * fp;
    float CB = c2 * ebs * dn3 * fp;

    if (act) {
        float* orow = out + (size_t)i * D;
        orow[lane]      = fmaf(CA, acc0, CB * bl0);
        orow[lane + 16] = fmaf(CA, acc1, CB * bl1);
        orow[lane + 32] = fmaf(CA, acc2, CB * bl2);
    }
}

// ---------- fallback path (atomic scatter + standalone node) ----------
__global__ void k_init_atomic(float* __restrict__ den, float* __restrict__ num, int n)
{
    int i = blockIdx.x * blockDim.x + threadIdx.x;
    if (i >= n) return;
    den[i] = 0.0f;
    float4* nr = reinterpret_cast<float4*>(num) + (size_t)i * DQ;
    float4 z = make_float4(0.f, 0.f, 0.f, 0.f);
#pragma unroll
    for (int q = 0; q < DQ; ++q) nr[q] = z;
}

__global__ void k_edge_atomic(const float* __restrict__ x, const float* __restrict__ gam,
                              const int* __restrict__ src, const int* __restrict__ dst,
                              const float* __restrict__ w,
                              float* __restrict__ num, float* __restrict__ den, int E)
{
    long long t = (long long)blockIdx.x * blockDim.x + threadIdx.x;
    int e = (int)(t / DQ);
    if (e >= E) return;
    int part = (int)(t % DQ);
    int s = src[e];
    int d = dst[e];
    float we = w[e];
    float g  = gam[s];
    float4 xv = reinterpret_cast<const float4*>(x)[(size_t)s * DQ + part];
    float c = we * g;
    float* np_ = num + (size_t)d * D + part * 4;
    atomicAdd(np_ + 0, c * xv.x);
    atomicAdd(np_ + 1, c * xv.y);
    atomicAdd(np_ + 2, c * xv.z);
    atomicAdd(np_ + 3, c * xv.w);
    if (part == 0) atomicAdd(den + d, fabsf(we) * (g - 1.0f));
}

__global__ __launch_bounds__(256) void k_node_fb(
    float* __restrict__ out,
    const float* __restrict__ den,
    const float* __restrict__ h_init,
    const float* __restrict__ Wm,
    const float* __restrict__ bias, int n)
{
    __shared__ float Ws[D * WSTR];
    __shared__ float bs[D];
    __shared__ float aLds[NPB][WSTR];
    int t = threadIdx.x;
    for (int k = t; k < D * D; k += 256) Ws[(k / D) * WSTR + (k % D)] = Wm[k];
    if (t < D) bs[t] = bias[t];
    __syncthreads();

    int grp = t >> 4;
    int lane = t & 15;
    int i = blockIdx.x * NPB + grp;
    bool act = (i < n);

    auto gsum = [](float v) {
        v += __shfl_xor(v, 1, 16);
        v += __shfl_xor(v, 2, 16);
        v += __shfl_xor(v, 4, 16);
        v += __shfl_xor(v, 8, 16);
        return v;
    };
    auto hmp_scale = [](float s) {
        float nrm = sqrtf(s);
        float ncl = fmaxf(nrm, F_EPS);
        float m = fminf(ncl, 1.0f - 1e-7f);
        float sc = __fdividef(__fdividef(m, ncl),
                              1.0f + sqrtf(fmaxf(1.0f - m * m, 0.0f)));
        float rn = nrm * sc;
        if (rn > MAXNORM) sc *= MAXNORM / fmaxf(rn, F_EPS);
        return sc;
    };

    float a0 = 0.f, a1 = 0.f, a2 = 0.f;
    if (act) {
        float dinv = 1.0f / clampabs(den[i]);
        const float* nr = out + (size_t)i * D;
        a0 = nr[lane] * dinv;
        a1 = nr[lane + 16] * dinv;
        a2 = nr[lane + 32] * dinv;
    }
    float s1 = gsum(a0 * a0 + a1 * a1 + a2 * a2);
    float sc1 = hmp_scale(s1);
    a0 *= sc1; a1 *= sc1; a2 *= sc1;
    float sa = s1 * sc1 * sc1;

    float s2, sc2;
    {
        float b0 = 0.f, b1 = 0.f, b2 = 0.f;
        if (act) {
            const float* hr = h_init + (size_t)i * D;
            b0 = hr[lane];
            b1 = hr[lane + 16];
            b2 = hr[lane + 32];
        }
        float sb = gsum(b0 * b0 + b1 * b1 + b2 * b2);
        float ga = 2.0f / fmaxf(1.0f - sa, F_EPS);
        float gb = 2.0f / fmaxf(1.0f - sb, F_EPS);
        const float wa = 0.9f, wb = 0.1f;
        float dinv = 1.0f / clampabs(wa * (ga - 1.0f) + wb * (gb - 1.0f));
        float ca = wa * ga * dinv, cb = wb * gb * dinv;
        a0 = ca * a0 + cb * b0;
        a1 = ca * a1 + cb * b1;
        a2 = ca * a2 + cb * b2;
        s2 = gsum(a0 * a0 + a1 * a1 + a2 * a2);
        sc2 = hmp_scale(s2);
        a0 *= sc2; a1 *= sc2; a2 *= sc2;
    }
    float xn = fmaxf(sqrtf(s2) * sc2, F_EPS);

    aLds[grp][lane]      = a0;
    aLds[grp][lane + 16] = a1;
    aLds[grp][lane + 32] = a2;
    __syncthreads();

    const float4* av4 = reinterpret_cast<const float4*>(&aLds[grp][0]);
    const float4* w04 = reinterpret_cast<const float4*>(&Ws[lane * WSTR]);
    const float4* w14 = reinterpret_cast<const float4*>(&Ws[(lane + 16) * WSTR]);
    const float4* w24 = reinterpret_cast<const float4*>(&Ws[(lane + 32) * WSTR]);
    float acc0 = 0.f, acc1 = 0.f, acc2 = 0.f;
#pragma unroll
    for (int kq = 0; kq < DQ; ++kq) {
        float4 a4 = av4[kq];
        float4 x0 = w04[kq];
        float4 x1 = w14[kq];
        float4 x2 = w24[kq];
        acc0 = fmaf(x0.x, a4.x, acc0); acc0 = fmaf(x0.y, a4.y, acc0);
        acc0 = fmaf(x0.z, a4.z, acc0); acc0 = fmaf(x0.w, a4.w, acc0);
        acc1 = fmaf(x1.x, a4.x, acc1); acc1 = fmaf(x1.y, a4.y, acc1);
        acc1 = fmaf(x1.z, a4.z, acc1); acc1 = fmaf(x1.w, a4.w, acc1);
        acc2 = fmaf(x2.x, a4.x, acc2); acc2 = fmaf(x2.y, a4.y, acc2);
        acc2 = fmaf(x2.z, a4.z, acc2); acc2 = fmaf(x2.w, a4.w, acc2);
    }
    float bl0 = bs[lane], bl1 = bs[lane + 16], bl2 = bs[lane + 32];
    float smx = gsum(acc0 * acc0 + acc1 * acc1 + acc2 * acc2);
    float xyr = gsum(acc0 * bl0 + acc1 * bl1 + acc2 * bl2);
    float bn2 = gsum(bl0 * bl0 + bl1 * bl1 + bl2 * bl2);

    float mxnr = sqrtf(smx);
    float mxn = fmaxf(mxnr, F_EPS);
    float tt = fast_tanh(__fdividef(mxn, xn) * fast_atanh(xn));
    float sc = __fdividef(tt, mxn);
    float rn = mxnr * sc;
    if (rn > MAXNORM) sc *= MAXNORM / fmaxf(rn, F_EPS);

    float bn  = fmaxf(sqrtf(bn2), F_EPS);
    float ebs = __fdividef(fast_tanh(bn), bn);
    float y2  = ebs * ebs * bn2;

    float x2v = sc * sc * smx;
    float xy = sc * ebs * xyr;
    float c1 = 1.0f + 2.0f * xy + y2;
    float c2 = 1.0f - x2v;
    float dn3 = 1.0f / fmaxf(1.0f + 2.0f * xy + x2v * y2, F_EPS);

    float s3 = dn3 * dn3 * (c1 * c1 * sc * sc * smx
                            + 2.0f * c1 * c2 * sc * ebs * xyr
                            + c2 * c2 * ebs * ebs * bn2);
    float nrm3 = sqrtf(s3);
    float fp = (nrm3 > MAXNORM) ? (MAXNORM / fmaxf(nrm3, F_EPS)) : 1.0f;

    float CA = c1 * sc * dn3 * fp;
    float CB = c2 * ebs * dn3 * fp;

    if (act) {
        float* orow = out + (size_t)i * D;
        orow[lane]      = fmaf(CA, acc0, CB * bl0);
        orow[lane + 16] = fmaf(CA, acc1, CB * bl1);
        orow[lane + 32] = fmaf(CA, acc2, CB * bl2);
    }
}

extern "C" void kernel_launch(void* const* d_in, const int* in_sizes, int n_in,
                              void* d_out, int out_size, void* d_ws, size_t ws_size,
                              hipStream_t stream)
{
    const float* x      = (const float*)d_in[0];
    const float* h_init = (const float*)d_in[1];
    const float* edge_w = (const float*)d_in[2];
    const float* W      = (const float*)d_in[3];
    const float* bias   = (const float*)d_in[4];
    const int*   esrc   = (const int*)d_in[5];
    const int*   edst   = (const int*)d_in[6];
    float* out = (float*)d_out;

    int n = in_sizes[0] / D;
    int E = in_sizes[2];
    int nb = (n + SPAN - 1) >> SHIFT;

    // ws layout
    char* p = (char*)d_ws;
    float* gam    = (float*)p;             p += (size_t)n * 4;
    float* den    = (float*)p;             p += (size_t)n * 4;
    int*   ghist  = (int*)p;               p += (size_t)nb * 4;
    int*   gstart = (int*)p;               p += (size_t)(nb + 1) * 4;
    int*   gcur   = (int*)p;               p += (size_t)nb * 4;
    int*   starts = (int*)p;               p += (size_t)(n + 1) * 4;
    p = (char*)(((uintptr_t)p + 127) & ~(uintptr_t)127);  // align 128
    int2*  seg    = (int2*)p;              p += (size_t)E * 8;
    int2*  seg2   = (int2*)p;              p += (size_t)E * 8;
    size_t need1 = (size_t)(p - (char*)d_ws);
    ushort4* ybf = (ushort4*)seg;          // aliases seg (dead after k_sortb)
    bool ybf_fits = ((size_t)E * 8 >= (size_t)n * YROW * 8);

    k_gamma<<<(n + 255) / 256, 256, 0, stream>>>(x, gam, ghist, n, nb);

    bool shape_ok = (nb <= 1024) && (n < (1 << 24));
    if (shape_ok && ybf_fits && need1 <= ws_size) {
        k_hist<<<(E + HCH - 1) / HCH, PTH, 0, stream>>>(edst, ghist, E, nb);
        k_scanb<<<1, 1024, 0, stream>>>(ghist, gstart, gcur, nb, E);
        k_part<<<(E + PCH - 1) / PCH, PTH, 0, stream>>>(esrc, edst, edge_w, gam, gcur, seg, E, nb);
        k_sortb<<<nb, 256, 0, stream>>>(seg, gstart, starts, seg2, n, E);
        long long pt = (long long)n * YROW;
        k_prep<<<(int)((pt + 255) / 256), 256, 0, stream>>>(x, gam, ybf, n);
        k_fuse<<<(n + NPB - 1) / NPB, 256, 0, stream>>>(
            ybf, starts, seg2, h_init, W, bias, out, n, E);
    } else {
        k_init_atomic<<<(n + 255) / 256, 256, 0, stream>>>(den, out, n);
        long long tot = (long long)E * DQ;
        k_edge_atomic<<<(int)((tot + 255) / 256), 256, 0, stream>>>(x, gam, esrc, edst, edge_w, out, den, E);
        k_node_fb<<<(n + NPB - 1) / NPB, 256, 0, stream>>>(out, den, h_init, W, bias, n);
    }
}

// Round 21
// 131.764 us; speedup vs baseline: 1.0978x; 1.0752x over previous
//
#include <hip/hip_runtime.h>
#include <math.h>

#define D  48
#define DQ 12        // D/4
#define SPAN 128     // nodes per bucket
#define SHIFT 7      // log2(SPAN)
#define PCH  8192    // edges per partition block
#define HCH  8192    // edges per histogram block
#define PTH  512     // threads for hist/part
#define NPB  16      // nodes per k_fuse block (16 threads/node)
#define WSTR 52      // LDS row stride (16B-aligned, low-conflict float4 reads)
#define YROW 16      // ybf row: 12 x ushort4 bf16(g*x) + 4 pad slots = 128B (shift addressing)

constexpr float F_EPS   = 1e-15f;
constexpr float MAXNORM = 1.0f - 1e-5f;

__device__ __forceinline__ float clampabs(float x) {
    return (x >= 0.0f) ? fmaxf(x, 1e-10f) : fminf(x, -1e-10f);
}

__device__ __forceinline__ unsigned short f2bf(float f) {
    unsigned u = __float_as_uint(f);
    u += 0x7FFFu + ((u >> 16) & 1u);
    return (unsigned short)(u >> 16);
}

__device__ __forceinline__ float bf2f(unsigned short u) {
    return __uint_as_float(((unsigned)u) << 16);
}

// fast tanh for x>=0 via hw exp (overflow-safe); fast atanh for 0<=x<1
__device__ __forceinline__ float fast_tanh(float x) {
    float e = __expf(2.0f * x);
    return 1.0f - __fdividef(2.0f, e + 1.0f);
}
__device__ __forceinline__ float fast_atanh(float x) {
    x = fminf(x, 1.0f - 1e-7f);
    return 0.5f * __logf(__fdividef(1.0f + x, 1.0f - x));
}

// ---------- per-node gamma + zero bucket histogram ----------
__global__ void k_gamma(const float* __restrict__ x, float* __restrict__ gam,
                        int* __restrict__ ghist, int n, int nb)
{
    int i = blockIdx.x * blockDim.x + threadIdx.x;
    if (i < nb) ghist[i] = 0;
    if (i >= n) return;
    const float4* xr = reinterpret_cast<const float4*>(x) + (size_t)i * DQ;
    float s = 0.0f;
#pragma unroll
    for (int q = 0; q < DQ; ++q) {
        float4 v = xr[q];
        s += v.x * v.x + v.y * v.y + v.z * v.z + v.w * v.w;
    }
    gam[i] = 2.0f / fmaxf(1.0f - s, F_EPS);
}

// ---------- bucket histogram (LDS-staged) ----------
__global__ __launch_bounds__(PTH) void k_hist(const int* __restrict__ dst,
                                              int* __restrict__ ghist, int E, int nb)
{
    __shared__ int h[1024];
    int t = threadIdx.x;
    for (int i = t; i < 1024; i += PTH) h[i] = 0;
    __syncthreads();
    int base = blockIdx.x * HCH;
#pragma unroll 4
    for (int k = 0; k < HCH / PTH; ++k) {
        int i = base + k * PTH + t;
        if (i < E) {
            unsigned b = ((unsigned)dst[i]) >> SHIFT;
            if (b < 1024u) atomicAdd(&h[b], 1);
        }
    }
    __syncthreads();
    for (int i = t; i < nb; i += PTH) {
        int c = h[i];
        if (c) atomicAdd(&ghist[i], c);
    }
}

// ---------- exclusive scan of bucket counts (single block, nb <= 1024) ----------
__global__ __launch_bounds__(1024) void k_scanb(const int* __restrict__ ghist,
                                                int* __restrict__ gstart,
                                                int* __restrict__ gcur, int nb, int E)
{
    __shared__ int sh[1024];
    int t = threadIdx.x;
    int v = (t < nb) ? ghist[t] : 0;
    sh[t] = v;
    __syncthreads();
    for (int off = 1; off < 1024; off <<= 1) {
        int a = sh[t];
        int b = (t >= off) ? sh[t - off] : 0;
        __syncthreads();
        sh[t] = a + b;
        __syncthreads();
    }
    if (t < nb) { int s = sh[t] - v; gstart[t] = s; gcur[t] = s; }
    if (t == 0) gstart[nb] = E;
}

// ---------- partition: records carry bf16(w) and bf16(|w|(g-1)) ----------
__global__ __launch_bounds__(PTH) void k_part(const int* __restrict__ src,
                                              const int* __restrict__ dst,
                                              const float* __restrict__ w,
                                              const float* __restrict__ gam,
                                              int* __restrict__ gcur,
                                              int2* __restrict__ seg, int E, int nb)
{
    __shared__ int hist[1024];
    __shared__ int base_[1024];
    __shared__ int lcur[1024];
    int t = threadIdx.x;
    for (int i = t; i < 1024; i += PTH) { hist[i] = 0; base_[i] = 0; lcur[i] = 0; }
    __syncthreads();
    int b0 = blockIdx.x * PCH;
#pragma unroll 4
    for (int k = 0; k < PCH / PTH; ++k) {
        int i = b0 + k * PTH + t;
        if (i < E) {
            unsigned b = ((unsigned)dst[i]) >> SHIFT;
            if (b < 1024u) atomicAdd(&hist[b], 1);
        }
    }
    __syncthreads();
    for (int i = t; i < nb; i += PTH) {
        int c = hist[i];
        if (c) base_[i] = atomicAdd(&gcur[i], c);
    }
    __syncthreads();
#pragma unroll 4
    for (int k = 0; k < PCH / PTH; ++k) {
        int i = b0 + k * PTH + t;
        if (i < E) {
            int d = dst[i];
            unsigned b = ((unsigned)d) >> SHIFT;
            if (b < 1024u) {
                int s = src[i];
                float wv = w[i];
                float g  = gam[s];                 // hot 400KB array (L2-resident)
                unsigned short wb  = f2bf(wv);
                unsigned short wdb = f2bf(fabsf(wv) * (g - 1.0f));
                int pos = base_[b] + atomicAdd(&lcur[b], 1);
                if (pos >= 0 && pos < E) {
                    int2 r;
                    r.x = ((d & (SPAN - 1)) << 24) | (s & 0xFFFFFF);
                    r.y = ((unsigned)wb << 16) | wdb;
                    seg[pos] = r;
                }
            }
        }
    }
}

// ---------- per-bucket LDS counting sort -> exact per-node order + starts ----------
__global__ __launch_bounds__(256) void k_sortb(
    const int2* __restrict__ seg, const int* __restrict__ gstart,
    int* __restrict__ starts, int2* __restrict__ seg2, int n, int E)
{
    __shared__ int hist[SPAN];
    __shared__ int sb[SPAN];
    __shared__ int cur[SPAN];
    int b = blockIdx.x;
    int t = threadIdx.x;
    if (b == 0 && t == 0) starts[n] = E;
    int segL = gstart[b], segR = gstart[b + 1];
    if (segL < 0) segL = 0;
    if (segR > E) segR = E;
    if (t < SPAN) hist[t] = 0;
    __syncthreads();
    {
        int j = segL + t;
        for (; j + 768 < segR; j += 1024) {
            unsigned d0 = ((unsigned)seg[j      ].x) >> 24;
            unsigned d1 = ((unsigned)seg[j + 256].x) >> 24;
            unsigned d2 = ((unsigned)seg[j + 512].x) >> 24;
            unsigned d3 = ((unsigned)seg[j + 768].x) >> 24;
            atomicAdd(&hist[d0], 1);
            atomicAdd(&hist[d1], 1);
            atomicAdd(&hist[d2], 1);
            atomicAdd(&hist[d3], 1);
        }
        for (; j < segR; j += 256) {
            unsigned dl = ((unsigned)seg[j].x) >> 24;
            atomicAdd(&hist[dl], 1);
        }
    }
    __syncthreads();
    if (t < SPAN) sb[t] = hist[t];
    __syncthreads();
    for (int off = 1; off < SPAN; off <<= 1) {
        int a = 0;
        if (t < SPAN) { a = sb[t]; if (t >= off) a += sb[t - off]; }
        __syncthreads();
        if (t < SPAN) sb[t] = a;
        __syncthreads();
    }
    if (t < SPAN) {
        int ls = sb[t] - hist[t];
        cur[t] = segL + ls;
        int node = b * SPAN + t;
        if (node < n) starts[node] = segL + ls;
    }
    __syncthreads();
    {
        int j = segL + t;
        for (; j + 768 < segR; j += 1024) {
            int2 r0 = seg[j      ];
            int2 r1 = seg[j + 256];
            int2 r2 = seg[j + 512];
            int2 r3 = seg[j + 768];
            int p0 = atomicAdd(&cur[((unsigned)r0.x) >> 24], 1);
            int p1 = atomicAdd(&cur[((unsigned)r1.x) >> 24], 1);
            int p2 = atomicAdd(&cur[((unsigned)r2.x) >> 24], 1);
            int p3 = atomicAdd(&cur[((unsigned)r3.x) >> 24], 1);
            if (p0 >= 0 && p0 < E) seg2[p0] = make_int2(r0.x & 0xFFFFFF, r0.y);
            if (p1 >= 0 && p1 < E) seg2[p1] = make_int2(r1.x & 0xFFFFFF, r1.y);
            if (p2 >= 0 && p2 < E) seg2[p2] = make_int2(r2.x & 0xFFFFFF, r2.y);
            if (p3 >= 0 && p3 < E) seg2[p3] = make_int2(r3.x & 0xFFFFFF, r3.y);
        }
        for (; j < segR; j += 256) {
            int2 r = seg[j];
            int pos = atomicAdd(&cur[((unsigned)r.x) >> 24], 1);
            if (pos >= 0 && pos < E) seg2[pos] = make_int2(r.x & 0xFFFFFF, r.y);
        }
    }
}

// ---------- k_prep: 128B-aligned ybf rows: 12x bf16(g*x) + 4 pad slots ----------
__global__ __launch_bounds__(256) void k_prep(const float* __restrict__ x,
                                              const float* __restrict__ gam,
                                              ushort4* __restrict__ ybf, int n)
{
    long long t = (long long)blockIdx.x * blockDim.x + threadIdx.x;
    int node = (int)(t / YROW);
    if (node >= n) return;
    int slot = (int)(t % YROW);
    ushort4 o;
    if (slot < 12) {
        float g = gam[node];
        float4 v = reinterpret_cast<const float4*>(x)[(size_t)node * DQ + slot];
        o.x = f2bf(v.x * g);
        o.y = f2bf(v.y * g);
        o.z = f2bf(v.z * g);
        o.w = f2bf(v.w * g);
    } else {
        o.x = 0; o.y = 0; o.z = 0; o.w = 0;   // pad (never read)
    }
    ybf[(size_t)node * YROW + slot] = o;
}

// ---------- fused gather + node math: 16 lanes/node, 4-wide, den from record ----------
__global__ __launch_bounds__(256) void k_fuse(
    const ushort4* __restrict__ ybf,
    const int* __restrict__ starts,
    const int2* __restrict__ srec,
    const float* __restrict__ h_init,
    const float* __restrict__ Wm,
    const float* __restrict__ bias,
    float* __restrict__ out, int n, int E)
{
    __shared__ float Ws[D * WSTR];
    __shared__ float bs[D];
    __shared__ float aLds[NPB][WSTR];
    int t = threadIdx.x;
    for (int k = t; k < D * D; k += 256) Ws[(k / D) * WSTR + (k % D)] = Wm[k];
    if (t < D) bs[t] = bias[t];

    int grp = t >> 4;
    int lane = t & 15;
    int i = blockIdx.x * NPB + grp;
    bool act = (i < n);
    bool numl = (lane < 12);

    auto gsum = [](float v) {
        v += __shfl_xor(v, 1, 16);
        v += __shfl_xor(v, 2, 16);
        v += __shfl_xor(v, 4, 16);
        v += __shfl_xor(v, 8, 16);
        return v;
    };
    auto hmp_scale = [](float s) {     // tanh(0.5*atanh(m))/m with project
        float nrm = sqrtf(s);
        float ncl = fmaxf(nrm, F_EPS);
        float m = fminf(ncl, 1.0f - 1e-7f);
        float sc = __fdividef(__fdividef(m, ncl),
                              1.0f + sqrtf(fmaxf(1.0f - m * m, 0.0f)));
        float rn = nrm * sc;
        if (rn > MAXNORM) sc *= MAXNORM / fmaxf(rn, F_EPS);
        return sc;
    };

    // ---- gather: lanes 0-11 fetch row slots (addr = r.x<<7 | lane<<3 —
    // shift-only addressing, the YROW=12 mul chain was a VALU hog);
    // lanes 12-15 idle on loads; den accumulated by ALL lanes from the
    // broadcast record bits (free).
    int j0 = 0, j1 = 0;
    if (act) {
        j0 = starts[i]; j1 = starts[i + 1];
        if (j0 < 0) j0 = 0;
        if (j1 > E) j1 = E;
    }
    float4 acc = make_float4(0.f, 0.f, 0.f, 0.f);
    float dacc = 0.f;
    int j = j0;
    for (; j + 3 < j1; j += 4) {
        int2 r0 = srec[j];
        int2 r1 = srec[j + 1];
        int2 r2 = srec[j + 2];
        int2 r3 = srec[j + 3];
        if (numl) {
            ushort4 a0 = ybf[((size_t)r0.x << 4) + lane];
            ushort4 a1 = ybf[((size_t)r1.x << 4) + lane];
            ushort4 a2 = ybf[((size_t)r2.x << 4) + lane];
            ushort4 a3 = ybf[((size_t)r3.x << 4) + lane];
            float w0 = bf2f((unsigned short)(((unsigned)r0.y) >> 16));
            float w1 = bf2f((unsigned short)(((unsigned)r1.y) >> 16));
            float w2 = bf2f((unsigned short)(((unsigned)r2.y) >> 16));
            float w3 = bf2f((unsigned short)(((unsigned)r3.y) >> 16));
            acc.x = fmaf(w0, bf2f(a0.x), acc.x);
            acc.y = fmaf(w0, bf2f(a0.y), acc.y);
            acc.z = fmaf(w0, bf2f(a0.z), acc.z);
            acc.w = fmaf(w0, bf2f(a0.w), acc.w);
            acc.x = fmaf(w1, bf2f(a1.x), acc.x);
            acc.y = fmaf(w1, bf2f(a1.y), acc.y);
            acc.z = fmaf(w1, bf2f(a1.z), acc.z);
            acc.w = fmaf(w1, bf2f(a1.w), acc.w);
            acc.x = fmaf(w2, bf2f(a2.x), acc.x);
            acc.y = fmaf(w2, bf2f(a2.y), acc.y);
            acc.z = fmaf(w2, bf2f(a2.z), acc.z);
            acc.w = fmaf(w2, bf2f(a2.w), acc.w);
            acc.x = fmaf(w3, bf2f(a3.x), acc.x);
            acc.y = fmaf(w3, bf2f(a3.y), acc.y);
            acc.z = fmaf(w3, bf2f(a3.z), acc.z);
            acc.w = fmaf(w3, bf2f(a3.w), acc.w);
        }
        dacc += bf2f((unsigned short)(((unsigned)r0.y) & 0xFFFF))
              + bf2f((unsigned short)(((unsigned)r1.y) & 0xFFFF))
              + bf2f((unsigned short)(((unsigned)r2.y) & 0xFFFF))
              + bf2f((unsigned short)(((unsigned)r3.y) & 0xFFFF));
    }
    for (; j < j1; ++j) {
        int2 r0 = srec[j];
        if (numl) {
            ushort4 a0 = ybf[((size_t)r0.x << 4) + lane];
            float w0 = bf2f((unsigned short)(((unsigned)r0.y) >> 16));
            acc.x = fmaf(w0, bf2f(a0.x), acc.x);
            acc.y = fmaf(w0, bf2f(a0.y), acc.y);
            acc.z = fmaf(w0, bf2f(a0.z), acc.z);
            acc.w = fmaf(w0, bf2f(a0.w), acc.w);
        }
        dacc += bf2f((unsigned short)(((unsigned)r0.y) & 0xFFFF));
    }
    float dv = dacc;   // identical in every lane of the group

    // redistribute num fragments (4p..4p+3) -> per-lane elems {l,l+16,l+32}
    if (numl)
        reinterpret_cast<float4*>(&aLds[grp][0])[lane] = acc;
    __syncthreads();

    // ---- node math
    float dinv = 1.0f / clampabs(dv);
    float a0 = aLds[grp][lane]      * dinv;
    float a1 = aLds[grp][lane + 16] * dinv;
    float a2 = aLds[grp][lane + 32] * dinv;

    float s1 = gsum(a0 * a0 + a1 * a1 + a2 * a2);
    float sc1 = hmp_scale(s1);
    a0 *= sc1; a1 *= sc1; a2 *= sc1;
    float sa = s1 * sc1 * sc1;

    float s2, sc2;
    {
        float b0 = 0.f, b1 = 0.f, b2 = 0.f;
        if (act) {
            const float* hr = h_init + (size_t)i * D;
            b0 = hr[lane];
            b1 = hr[lane + 16];
            b2 = hr[lane + 32];
        }
        float sb = gsum(b0 * b0 + b1 * b1 + b2 * b2);
        float ga = 2.0f / fmaxf(1.0f - sa, F_EPS);
        float gb = 2.0f / fmaxf(1.0f - sb, F_EPS);
        const float wa = 0.9f, wb = 0.1f;
        float dinv2 = 1.0f / clampabs(wa * (ga - 1.0f) + wb * (gb - 1.0f));
        float ca = wa * ga * dinv2, cb = wb * gb * dinv2;
        a0 = ca * a0 + cb * b0;
        a1 = ca * a1 + cb * b1;
        a2 = ca * a2 + cb * b2;
        s2 = gsum(a0 * a0 + a1 * a1 + a2 * a2);
        sc2 = hmp_scale(s2);
        a0 *= sc2; a1 *= sc2; a2 *= sc2;
    }
    float xn = fmaxf(sqrtf(s2) * sc2, F_EPS);

    // restage projected a for the float4 matvec
    aLds[grp][lane]      = a0;
    aLds[grp][lane + 16] = a1;
    aLds[grp][lane + 32] = a2;
    __syncthreads();

    const float4* av4 = reinterpret_cast<const float4*>(&aLds[grp][0]);
    const float4* w04 = reinterpret_cast<const float4*>(&Ws[lane * WSTR]);
    const float4* w14 = reinterpret_cast<const float4*>(&Ws[(lane + 16) * WSTR]);
    const float4* w24 = reinterpret_cast<const float4*>(&Ws[(lane + 32) * WSTR]);
    float acc0 = 0.f, acc1 = 0.f, acc2 = 0.f;
#pragma unroll
    for (int kq = 0; kq < DQ; ++kq) {
        float4 a4 = av4[kq];
        float4 x0 = w04[kq];
        float4 x1 = w14[kq];
        float4 x2 = w24[kq];
        acc0 = fmaf(x0.x, a4.x, acc0); acc0 = fmaf(x0.y, a4.y, acc0);
        acc0 = fmaf(x0.z, a4.z, acc0); acc0 = fmaf(x0.w, a4.w, acc0);
        acc1 = fmaf(x1.x, a4.x, acc1); acc1 = fmaf(x1.y, a4.y, acc1);
        acc1 = fmaf(x1.z, a4.z, acc1); acc1 = fmaf(x1.w, a4.w, acc1);
        acc2 = fmaf(x2.x, a4.x, acc2); acc2 = fmaf(x2.y, a4.y, acc2);
        acc2 = fmaf(x2.z, a4.z, acc2); acc2 = fmaf(x2.w, a4.w, acc2);
    }
    float bl0 = bs[lane], bl1 = bs[lane + 16], bl2 = bs[lane + 32];
    float smx = gsum(acc0 * acc0 + acc1 * acc1 + acc2 * acc2);
    float xyr = gsum(acc0 * bl0 + acc1 * bl1 + acc2 * bl2);
    float bn2 = gsum(bl0 * bl0 + bl1 * bl1 + bl2 * bl2);

    float mxnr = sqrtf(smx);
    float mxn = fmaxf(mxnr, F_EPS);
    float tt = fast_tanh(__fdividef(mxn, xn) * fast_atanh(xn));
    float sc = __fdividef(tt, mxn);
    float rn = mxnr * sc;
    if (rn > MAXNORM) sc *= MAXNORM / fmaxf(rn, F_EPS);

    float bn  = fmaxf(sqrtf(bn2), F_EPS);
    float ebs = __fdividef(fast_tanh(bn), bn);
    float y2  = ebs * ebs * bn2;

    float x2v = sc * sc * smx;
    float xy = sc * ebs * xyr;
    float c1 = 1.0f + 2.0f * xy + y2;
    float c2 = 1.0f - x2v;
    float dn3 = 1.0f / fmaxf(1.0f + 2.0f * xy + x2v * y2, F_EPS);

    float s3 = dn3 * dn3 * (c1 * c1 * sc * sc * smx
                            + 2.0f * c1 * c2 * sc * ebs * xyr
                            + c2 * c2 * ebs * ebs * bn2);
    float nrm3 = sqrtf(s3);
    float fp = (nrm3 > MAXNORM) ? (MAXNORM / fmaxf(nrm3, F_EPS)) : 1.0f;

    float CA = c1 * sc * dn3 * fp;
    float CB = c2 * ebs * dn3 * fp;

    if (act) {
        float* orow = out + (size_t)i * D;
        orow[lane]      = fmaf(CA, acc0, CB * bl0);
        orow[lane + 16] = fmaf(CA, acc1, CB * bl1);
        orow[lane + 32] = fmaf(CA, acc2, CB * bl2);
    }
}

// ---------- fallback path (atomic scatter + standalone node) ----------
__global__ void k_init_atomic(float* __restrict__ den, float* __restrict__ num, int n)
{
    int i = blockIdx.x * blockDim.x + threadIdx.x;
    if (i >= n) return;
    den[i] = 0.0f;
    float4* nr = reinterpret_cast<float4*>(num) + (size_t)i * DQ;
    float4 z = make_float4(0.f, 0.f, 0.f, 0.f);
#pragma unroll
    for (int q = 0; q < DQ; ++q) nr[q] = z;
}

__global__ void k_edge_atomic(const float* __restrict__ x, const float* __restrict__ gam,
                              const int* __restrict__ src, const int* __restrict__ dst,
                              const float* __restrict__ w,
                              float* __restrict__ num, float* __restrict__ den, int E)
{
    long long t = (long long)blockIdx.x * blockDim.x + threadIdx.x;
    int e = (int)(t / DQ);
    if (e >= E) return;
    int part = (int)(t % DQ);
    int s = src[e];
    int d = dst[e];
    float we = w[e];
    float g  = gam[s];
    float4 xv = reinterpret_cast<const float4*>(x)[(size_t)s * DQ + part];
    float c = we * g;
    float* np_ = num + (size_t)d * D + part * 4;
    atomicAdd(np_ + 0, c * xv.x);
    atomicAdd(np_ + 1, c * xv.y);
    atomicAdd(np_ + 2, c * xv.z);
    atomicAdd(np_ + 3, c * xv.w);
    if (part == 0) atomicAdd(den + d, fabsf(we) * (g - 1.0f));
}

__global__ __launch_bounds__(256) void k_node_fb(
    float* __restrict__ out,
    const float* __restrict__ den,
    const float* __restrict__ h_init,
    const float* __restrict__ Wm,
    const float* __restrict__ bias, int n)
{
    __shared__ float Ws[D * WSTR];
    __shared__ float bs[D];
    __shared__ float aLds[NPB][WSTR];
    int t = threadIdx.x;
    for (int k = t; k < D * D; k += 256) Ws[(k / D) * WSTR + (k % D)] = Wm[k];
    if (t < D) bs[t] = bias[t];
    __syncthreads();

    int grp = t >> 4;
    int lane = t & 15;
    int i = blockIdx.x * NPB + grp;
    bool act = (i < n);

    auto gsum = [](float v) {
        v += __shfl_xor(v, 1, 16);
        v += __shfl_xor(v, 2, 16);
        v += __shfl_xor(v, 4, 16);
        v += __shfl_xor(v, 8, 16);
        return v;
    };
    auto hmp_scale = [](float s) {
        float nrm = sqrtf(s);
        float ncl = fmaxf(nrm, F_EPS);
        float m = fminf(ncl, 1.0f - 1e-7f);
        float sc = __fdividef(__fdividef(m, ncl),
                              1.0f + sqrtf(fmaxf(1.0f - m * m, 0.0f)));
        float rn = nrm * sc;
        if (rn > MAXNORM) sc *= MAXNORM / fmaxf(rn, F_EPS);
        return sc;
    };

    float a0 = 0.f, a1 = 0.f, a2 = 0.f;
    if (act) {
        float dinv = 1.0f / clampabs(den[i]);
        const float* nr = out + (size_t)i * D;
        a0 = nr[lane] * dinv;
        a1 = nr[lane + 16] * dinv;
        a2 = nr[lane + 32] * dinv;
    }
    float s1 = gsum(a0 * a0 + a1 * a1 + a2 * a2);
    float sc1 = hmp_scale(s1);
    a0 *= sc1; a1 *= sc1; a2 *= sc1;
    float sa = s1 * sc1 * sc1;

    float s2, sc2;
    {
        float b0 = 0.f, b1 = 0.f, b2 = 0.f;
        if (act) {
            const float* hr = h_init + (size_t)i * D;
            b0 = hr[lane];
            b1 = hr[lane + 16];
            b2 = hr[lane + 32];
        }
        float sb = gsum(b0 * b0 + b1 * b1 + b2 * b2);
        float ga = 2.0f / fmaxf(1.0f - sa, F_EPS);
        float gb = 2.0f / fmaxf(1.0f - sb, F_EPS);
        const float wa = 0.9f, wb = 0.1f;
        float dinv = 1.0f / clampabs(wa * (ga - 1.0f) + wb * (gb - 1.0f));
        float ca = wa * ga * dinv, cb = wb * gb * dinv;
        a0 = ca * a0 + cb * b0;
        a1 = ca * a1 + cb * b1;
        a2 = ca * a2 + cb * b2;
        s2 = gsum(a0 * a0 + a1 * a1 + a2 * a2);
        sc2 = hmp_scale(s2);
        a0 *= sc2; a1 *= sc2; a2 *= sc2;
    }
    float xn = fmaxf(sqrtf(s2) * sc2, F_EPS);

    aLds[grp][lane]      = a0;
    aLds[grp][lane + 16] = a1;
    aLds[grp][lane + 32] = a2;
    __syncthreads();

    const float4* av4 = reinterpret_cast<const float4*>(&aLds[grp][0]);
    const float4* w04 = reinterpret_cast<const float4*>(&Ws[lane * WSTR]);
    const float4* w14 = reinterpret_cast<const float4*>(&Ws[(lane + 16) * WSTR]);
    const float4* w24 = reinterpret_cast<const float4*>(&Ws[(lane + 32) * WSTR]);
    float acc0 = 0.f, acc1 = 0.f, acc2 = 0.f;
#pragma unroll
    for (int kq = 0; kq < DQ; ++kq) {
        float4 a4 = av4[kq];
        float4 x0 = w04[kq];
        float4 x1 = w14[kq];
        float4 x2 = w24[kq];
        acc0 = fmaf(x0.x, a4.x, acc0); acc0 = fmaf(x0.y, a4.y, acc0);
        acc0 = fmaf(x0.z, a4.z, acc0); acc0 = fmaf(x0.w, a4.w, acc0);
        acc1 = fmaf(x1.x, a4.x, acc1); acc1 = fmaf(x1.y, a4.y, acc1);
        acc1 = fmaf(x1.z, a4.z, acc1); acc1 = fmaf(x1.w, a4.w, acc1);
        acc2 = fmaf(x2.x, a4.x, acc2); acc2 = fmaf(x2.y, a4.y, acc2);
        acc2 = fmaf(x2.z, a4.z, acc2); acc2 = fmaf(x2.w, a4.w, acc2);
    }
    float bl0 = bs[lane], bl1 = bs[lane + 16], bl2 = bs[lane + 32];
    float smx = gsum(acc0 * acc0 + acc1 * acc1 + acc2 * acc2);
    float xyr = gsum(acc0 * bl0 + acc1 * bl1 + acc2 * bl2);
    float bn2 = gsum(bl0 * bl0 + bl1 * bl1 + bl2 * bl2);

    float mxnr = sqrtf(smx);
    float mxn = fmaxf(mxnr, F_EPS);
    float tt = fast_tanh(__fdividef(mxn, xn) * fast_atanh(xn));
    float sc = __fdividef(tt, mxn);
    float rn = mxnr * sc;
    if (rn > MAXNORM) sc *= MAXNORM / fmaxf(rn, F_EPS);

    float bn  = fmaxf(sqrtf(bn2), F_EPS);
    float ebs = __fdividef(fast_tanh(bn), bn);
    float y2  = ebs * ebs * bn2;

    float x2v = sc * sc * smx;
    float xy = sc * ebs * xyr;
    float c1 = 1.0f + 2.0f * xy + y2;
    float c2 = 1.0f - x2v;
    float dn3 = 1.0f / fmaxf(1.0f + 2.0f * xy + x2v * y2, F_EPS);

    float s3 = dn3 * dn3 * (c1 * c1 * sc * sc * smx
                            + 2.0f * c1 * c2 * sc * ebs * xyr
                            + c2 * c2 * ebs * ebs * bn2);
    float nrm3 = sqrtf(s3);
    float fp = (nrm3 > MAXNORM) ? (MAXNORM / fmaxf(nrm3, F_EPS)) : 1.0f;

    float CA = c1 * sc * dn3 * fp;
    float CB = c2 * ebs * dn3 * fp;

    if (act) {
        float* orow = out + (size_t)i * D;
        orow[lane]      = fmaf(CA, acc0, CB * bl0);
        orow[lane + 16] = fmaf(CA, acc1, CB * bl1);
        orow[lane + 32] = fmaf(CA, acc2, CB * bl2);
    }
}

extern "C" void kernel_launch(void* const* d_in, const int* in_sizes, int n_in,
                              void* d_out, int out_size, void* d_ws, size_t ws_size,
                              hipStream_t stream)
{
    const float* x      = (const float*)d_in[0];
    const float* h_init = (const float*)d_in[1];
    const float* edge_w = (const float*)d_in[2];
    const float* W      = (const float*)d_in[3];
    const float* bias   = (const float*)d_in[4];
    const int*   esrc   = (const int*)d_in[5];
    const int*   edst   = (const int*)d_in[6];
    float* out = (float*)d_out;

    int n = in_sizes[0] / D;
    int E = in_sizes[2];
    int nb = (n + SPAN - 1) >> SHIFT;

    // ws layout
    char* p = (char*)d_ws;
    float* gam    = (float*)p;             p += (size_t)n * 4;
    float* den    = (float*)p;             p += (size_t)n * 4;
    int*   ghist  = (int*)p;               p += (size_t)nb * 4;
    int*   gstart = (int*)p;               p += (size_t)(nb + 1) * 4;
    int*   gcur   = (int*)p;               p += (size_t)nb * 4;
    int*   starts = (int*)p;               p += (size_t)(n + 1) * 4;
    p = (char*)(((uintptr_t)p + 127) & ~(uintptr_t)127);  // align 128
    int2*  seg    = (int2*)p;              p += (size_t)E * 8;
    int2*  seg2   = (int2*)p;              p += (size_t)E * 8;
    size_t need1 = (size_t)(p - (char*)d_ws);
    ushort4* ybf = (ushort4*)seg;          // aliases seg (dead after k_sortb)
    bool ybf_fits = ((size_t)E * 8 >= (size_t)n * YROW * 8);

    k_gamma<<<(n + 255) / 256, 256, 0, stream>>>(x, gam, ghist, n, nb);

    bool shape_ok = (nb <= 1024) && (n < (1 << 24));
    if (shape_ok && ybf_fits && need1 <= ws_size) {
        k_hist<<<(E + HCH - 1) / HCH, PTH, 0, stream>>>(edst, ghist, E, nb);
        k_scanb<<<1, 1024, 0, stream>>>(ghist, gstart, gcur, nb, E);
        k_part<<<(E + PCH - 1) / PCH, PTH, 0, stream>>>(esrc, edst, edge_w, gam, gcur, seg, E, nb);
        k_sortb<<<nb, 256, 0, stream>>>(seg, gstart, starts, seg2, n, E);
        long long pt = (long long)n * YROW;
        k_prep<<<(int)((pt + 255) / 256), 256, 0, stream>>>(x, gam, ybf, n);
        k_fuse<<<(n + NPB - 1) / NPB, 256, 0, stream>>>(
            ybf, starts, seg2, h_init, W, bias, out, n, E);
    } else {
        k_init_atomic<<<(n + 255) / 256, 256, 0, stream>>>(den, out, n);
        long long tot = (long long)E * DQ;
        k_edge_atomic<<<(int)((tot + 255) / 256), 256, 0, stream>>>(x, gam, esrc, edst, edge_w, out, den, E);
        k_node_fb<<<(n + NPB - 1) / NPB, 256, 0, stream>>>(out, den, h_init, W, bias, n);
    }
}